// Round 1
// baseline (838.902 us; speedup 1.0000x reference)
//
#include <hip/hip_runtime.h>

#define BB 2
#define NN 512
#define CC 256
#define OO 256
#define EE 18

// workspace layout (float offsets)
#define OFF_SF   0
#define OFF_NBR  (OFF_SF + BB*NN*OO)
#define OFF_AI   (OFF_NBR + BB*NN*OO)
#define OFF_AJT  (OFF_AI + BB*NN*64)
#define OFF_EGXT (OFF_AJT + BB*64*NN)
#define OFF_MSG  (OFF_EGXT + BB*64*NN)
#define WS_FLOATS (OFF_MSG + BB*NN*OO)

__device__ __forceinline__ unsigned short f2bf(float f) {
  unsigned u = __float_as_uint(f);
  u += 0x7fffu + ((u >> 16) & 1u);          // RNE
  return (unsigned short)(u >> 16);
}
__device__ __forceinline__ float bflo(unsigned v){ return __uint_as_float(v << 16); }
__device__ __forceinline__ float bfhi(unsigned v){ return __uint_as_float(v & 0xffff0000u); }

// dense layer: OUTV = relu(INV @ WARR + BARR), weights broadcast from LDS (float4)
#define DENSE_RELU(OUTV, OUTN, INV, INN, WARR, BARR)                    \
  _Pragma("unroll")                                                     \
  for (int l = 0; l < OUTN; l += 4) {                                   \
    float4 a = *(const float4*)&BARR[l];                                \
    _Pragma("unroll")                                                   \
    for (int k = 0; k < INN; ++k) {                                     \
      float4 wv = *(const float4*)&WARR[k*OUTN + l];                    \
      a.x += INV[k]*wv.x; a.y += INV[k]*wv.y;                           \
      a.z += INV[k]*wv.z; a.w += INV[k]*wv.w;                           \
    }                                                                   \
    OUTV[l]=fmaxf(a.x,0.f); OUTV[l+1]=fmaxf(a.y,0.f);                   \
    OUTV[l+2]=fmaxf(a.z,0.f); OUTV[l+3]=fmaxf(a.w,0.f);                 \
  }

// dense layer accumulating into pre-initialized IOV, then relu in place
#define DENSE_ACC_RELU(IOV, OUTN, INV, INN, WARR)                       \
  _Pragma("unroll")                                                     \
  for (int l = 0; l < OUTN; l += 4) {                                   \
    float4 a = make_float4(IOV[l], IOV[l+1], IOV[l+2], IOV[l+3]);       \
    _Pragma("unroll")                                                   \
    for (int k = 0; k < INN; ++k) {                                     \
      float4 wv = *(const float4*)&WARR[k*OUTN + l];                    \
      a.x += INV[k]*wv.x; a.y += INV[k]*wv.y;                           \
      a.z += INV[k]*wv.z; a.w += INV[k]*wv.w;                           \
    }                                                                   \
    IOV[l]=fmaxf(a.x,0.f); IOV[l+1]=fmaxf(a.y,0.f);                     \
    IOV[l+2]=fmaxf(a.z,0.f); IOV[l+3]=fmaxf(a.w,0.f);                   \
  }

// ---------------------------------------------------------------------------
// K1: per-node linear transforms.
// outputs: self_feat [B,N,256], nbr [B,N,256], a_i [B,N,64],
//          a_jT [B,64,N], eg_xT [B,64,N] (transposed for coalesced phase-1 reads)
// ---------------------------------------------------------------------------
__global__ __launch_bounds__(256) void k_node(
    const float* __restrict__ x,
    const float* __restrict__ st_w, const float* __restrict__ st_b,
    const float* __restrict__ nt_w, const float* __restrict__ nt_b,
    const float* __restrict__ at_w1, const float* __restrict__ eg_w1,
    float* __restrict__ ws)
{
  __shared__ __align__(16) float xs[4*CC];
  const int t = threadIdx.x;
  const int g0 = blockIdx.x * 4;          // 4 nodes per block, 256 blocks
  for (int idx = t; idx < 4*CC; idx += 256) xs[idx] = x[(size_t)g0*CC + idx];
  __syncthreads();
  for (int col = t; col < 704; col += 256) {
    const float* W; int ldw;
    if (col < 256)      { W = st_w + col;                   ldw = 256; }
    else if (col < 512) { W = nt_w + (col - 256);           ldw = 256; }
    else if (col < 576) { W = at_w1 + (col - 512);          ldw = 64; }
    else if (col < 640) { W = at_w1 + 256*64 + (col - 576); ldw = 64; }
    else                { W = eg_w1 + (col - 640);          ldw = 64; }
    float a0=0.f, a1=0.f, a2=0.f, a3=0.f;
    #pragma unroll 8
    for (int k = 0; k < CC; ++k) {
      float w = W[(size_t)k*ldw];
      a0 += xs[k]*w; a1 += xs[CC+k]*w; a2 += xs[2*CC+k]*w; a3 += xs[3*CC+k]*w;
    }
    float av[4] = {a0,a1,a2,a3};
    #pragma unroll
    for (int m = 0; m < 4; ++m) {
      int g = g0 + m, bb = g >> 9, n = g & 511;
      if (col < 256)      ws[OFF_SF  + (size_t)g*OO + col]         = av[m] + st_b[col];
      else if (col < 512) ws[OFF_NBR + (size_t)g*OO + (col-256)]   = av[m] + nt_b[col-256];
      else if (col < 576) ws[OFF_AI  + (size_t)g*64 + (col-512)]   = av[m];
      else if (col < 640) ws[OFF_AJT + ((size_t)bb*64 + (col-576))*NN + n] = av[m];
      else                ws[OFF_EGXT+ ((size_t)bb*64 + (col-640))*NN + n] = av[m];
    }
  }
}

// ---------------------------------------------------------------------------
// K2: fused per-row edge kernel. 1 block per (i,b). 512 threads.
// Phase 1 (thread = j): edge MLP -> pe; attention MLP -> score; gate g1 -> LDS (bf16).
// Softmax across block. Phase 2 (thread = output column o, 2 j-groups):
// g2 = sigmoid(g1 . w2col) with w2col in registers, accumulate msg.
// ---------------------------------------------------------------------------
__global__ __launch_bounds__(512, 2) void k_edge(
    const int*   __restrict__ adj,
    const float* __restrict__ ef_g,
    const float* __restrict__ em_w1g, const float* __restrict__ em_b1g,
    const float* __restrict__ em_w2g, const float* __restrict__ em_b2g,
    const float* __restrict__ em_w3g, const float* __restrict__ em_b3g,
    const float* __restrict__ at_w1g, const float* __restrict__ at_b1g,
    const float* __restrict__ at_w2g, const float* __restrict__ at_b2g,
    const float* __restrict__ at_w3g, const float* __restrict__ at_b3g,
    const float* __restrict__ eg_w1g, const float* __restrict__ eg_b1g,
    const float* __restrict__ eg_w2g, const float* __restrict__ eg_b2g,
    float* __restrict__ ws)
{
  __shared__ __align__(16) float s_em_w1[EE*64];
  __shared__ __align__(16) float s_em_b1[64];
  __shared__ __align__(16) float s_em_w2[64*64];
  __shared__ __align__(16) float s_em_b2[64];
  __shared__ __align__(16) float s_em_w3[64*32];
  __shared__ __align__(16) float s_em_b3[32];
  __shared__ __align__(16) float s_at_w1e[32*64];
  __shared__ __align__(16) float s_at_b1[64];
  __shared__ __align__(16) float s_at_w2[64*32];
  __shared__ __align__(16) float s_at_b2[32];
  __shared__ __align__(16) float s_at_w3[32];
  __shared__ __align__(16) float s_eg_w1e[32*64];
  __shared__ __align__(16) float s_eg_b1[64];
  __shared__ __align__(16) unsigned short s_eg_w2[64*256];  // bf16
  __shared__ __align__(16) float s_eg_b2[256];
  __shared__ __align__(16) float s_ai[64];
  __shared__ __align__(16) float s_sc[NN];
  __shared__ __align__(16) float s_red[16];
  __shared__ __align__(16) unsigned short s_g1[NN][64];     // bf16, row = 128B
  __shared__ __align__(16) float s_msg[OO];

  const int t = threadIdx.x;
  const int i = blockIdx.x, b = blockIdx.y;

  // --- stage weights ---
  for (int idx = t; idx < EE*64;  idx += 512) s_em_w1[idx]  = em_w1g[idx];
  for (int idx = t; idx < 64*64;  idx += 512) s_em_w2[idx]  = em_w2g[idx];
  for (int idx = t; idx < 64*32;  idx += 512) s_em_w3[idx]  = em_w3g[idx];
  for (int idx = t; idx < 32*64;  idx += 512) s_at_w1e[idx] = at_w1g[512*64 + idx];
  for (int idx = t; idx < 64*32;  idx += 512) s_at_w2[idx]  = at_w2g[idx];
  for (int idx = t; idx < 32*64;  idx += 512) s_eg_w1e[idx] = eg_w1g[256*64 + idx];
  for (int idx = t; idx < 64*256; idx += 512) s_eg_w2[idx]  = f2bf(eg_w2g[idx]);
  if (t < 64) {
    s_em_b1[t] = em_b1g[t]; s_em_b2[t] = em_b2g[t];
    s_at_b1[t] = at_b1g[t]; s_eg_b1[t] = eg_b1g[t];
    s_ai[t]    = ws[OFF_AI + (size_t)(b*NN + i)*64 + t];
    if (t < 32) { s_em_b3[t] = em_b3g[t]; s_at_b2[t] = at_b2g[t]; s_at_w3[t] = at_w3g[t]; }
  }
  if (t < 256) s_eg_b2[t] = eg_b2g[t];
  __syncthreads();

  // ====================== phase 1: thread = edge j ======================
  const int j = t;
  const bool maskj = adj[(size_t)(b*NN + i)*NN + j] > 0;
  const float* efp = ef_g + ((size_t)(b*NN + i)*NN + j) * EE;

  float ef[EE];
  #pragma unroll
  for (int k = 0; k < EE/2; ++k) { float2 v = *(const float2*)(efp + 2*k); ef[2*k]=v.x; ef[2*k+1]=v.y; }

  float h1[64];
  DENSE_RELU(h1, 64, ef, EE, s_em_w1, s_em_b1)
  float h2[64];
  DENSE_RELU(h2, 64, h1, 64, s_em_w2, s_em_b2)
  float pe[32];
  DENSE_RELU(pe, 32, h2, 64, s_em_w3, s_em_b3)

  // attention score
  float t1[64];
  {
    const float* ajp = ws + OFF_AJT + (size_t)b*64*NN + j;
    #pragma unroll
    for (int l = 0; l < 64; ++l) t1[l] = s_ai[l] + ajp[(size_t)l*NN] + s_at_b1[l];
  }
  DENSE_ACC_RELU(t1, 64, pe, 32, s_at_w1e)
  float t2[32];
  DENSE_RELU(t2, 32, t1, 64, s_at_w2, s_at_b2)
  float sc = at_b3g[0];
  #pragma unroll
  for (int k = 0; k < 32; ++k) sc += t2[k]*s_at_w3[k];
  s_sc[j] = maskj ? sc : -1e9f;

  // gate g1 -> LDS bf16
  float g1[64];
  {
    const float* egp = ws + OFF_EGXT + (size_t)b*64*NN + j;
    #pragma unroll
    for (int l = 0; l < 64; ++l) g1[l] = egp[(size_t)l*NN] + s_eg_b1[l];
  }
  DENSE_ACC_RELU(g1, 64, pe, 32, s_eg_w1e)
  {
    uint4* row = (uint4*)&s_g1[j][0];
    #pragma unroll
    for (int q = 0; q < 8; ++q) {
      unsigned p0 = (unsigned)f2bf(g1[8*q+0]) | ((unsigned)f2bf(g1[8*q+1]) << 16);
      unsigned p1 = (unsigned)f2bf(g1[8*q+2]) | ((unsigned)f2bf(g1[8*q+3]) << 16);
      unsigned p2 = (unsigned)f2bf(g1[8*q+4]) | ((unsigned)f2bf(g1[8*q+5]) << 16);
      unsigned p3 = (unsigned)f2bf(g1[8*q+6]) | ((unsigned)f2bf(g1[8*q+7]) << 16);
      row[q] = make_uint4(p0,p1,p2,p3);
    }
  }
  __syncthreads();   // S1: scores + g1 visible

  // ====================== masked softmax over j ======================
  float v = s_sc[t];
  float m = v;
  #pragma unroll
  for (int d = 1; d < 64; d <<= 1) m = fmaxf(m, __shfl_xor(m, d));
  if ((t & 63) == 0) s_red[t >> 6] = m;
  __syncthreads();   // S2
  float mx = s_red[0];
  #pragma unroll
  for (int w = 1; w < 8; ++w) mx = fmaxf(mx, s_red[w]);
  float p = maskj ? __expf(v - mx) : 0.f;
  float sm = p;
  #pragma unroll
  for (int d = 1; d < 64; d <<= 1) sm += __shfl_xor(sm, d);
  __syncthreads();   // S3: all done reading s_red (max)
  if ((t & 63) == 0) s_red[t >> 6] = sm;
  s_sc[t] = p;       // own element; read by others only after S4
  __syncthreads();   // S4
  float den = 0.f;
  #pragma unroll
  for (int w = 0; w < 8; ++w) den += s_red[w];
  const float inv = den > 0.f ? 1.f/den : 0.f;

  // ====================== phase 2: thread = output column o ======================
  const int grp = t >> 8;          // 0: j 0..255, 1: j 256..511
  const int o   = t & 255;
  float w2c[64];
  #pragma unroll
  for (int k = 0; k < 64; ++k) w2c[k] = bflo((unsigned)s_eg_w2[k*256 + o] << 16 >> 16 << 16);
  // (the shifts fold to a single <<16; written simply:)
  #pragma unroll
  for (int k = 0; k < 64; ++k) w2c[k] = __uint_as_float(((unsigned)s_eg_w2[k*256 + o]) << 16);

  const float bo = s_eg_b2[o];
  const float* nbrb = ws + OFF_NBR + (size_t)b*NN*OO + o;
  float acc = 0.f;
  for (int j2 = grp*256; j2 < grp*256 + 256; ++j2) {
    float pj = s_sc[j2];           // uniform across wave
    if (pj > 0.f) {
      const uint4* row = (const uint4*)&s_g1[j2][0];
      float z = bo;
      #pragma unroll
      for (int q = 0; q < 8; ++q) {
        uint4 vv = row[q];
        z += bflo(vv.x)*w2c[8*q+0]; z += bfhi(vv.x)*w2c[8*q+1];
        z += bflo(vv.y)*w2c[8*q+2]; z += bfhi(vv.y)*w2c[8*q+3];
        z += bflo(vv.z)*w2c[8*q+4]; z += bfhi(vv.z)*w2c[8*q+5];
        z += bflo(vv.w)*w2c[8*q+6]; z += bfhi(vv.w)*w2c[8*q+7];
      }
      float g2 = 1.f/(1.f + __expf(-z));
      acc += pj * g2 * nbrb[(size_t)j2*OO];
    }
  }
  acc *= inv;  // fold softmax denominator once
  if (grp == 0) s_msg[o] = acc;
  __syncthreads();
  if (grp == 1) s_msg[o] += acc;
  __syncthreads();
  if (t < 256) ws[OFF_MSG + (size_t)(b*NN + i)*OO + t] = s_msg[t];
}

// ---------------------------------------------------------------------------
// K3: out = relu([self_feat | msg] @ cb_w1 + cb_b1) @ cb_w2 + cb_b2
// ---------------------------------------------------------------------------
__global__ __launch_bounds__(256) void k_out(
    const float* __restrict__ cb_w1, const float* __restrict__ cb_b1,
    const float* __restrict__ cb_w2, const float* __restrict__ cb_b2,
    const float* __restrict__ ws, float* __restrict__ out)
{
  __shared__ __align__(16) float comb[4][512];
  __shared__ __align__(16) float tmp[4][256];
  const int t = threadIdx.x;
  const int g0 = blockIdx.x * 4;
  for (int idx = t; idx < 4*256; idx += 256) {
    int mm = idx >> 8, c = idx & 255;
    comb[mm][c]       = ws[OFF_SF  + (size_t)(g0+mm)*OO + c];
    comb[mm][256 + c] = ws[OFF_MSG + (size_t)(g0+mm)*OO + c];
  }
  __syncthreads();
  const int o = t;
  {
    float b = cb_b1[o];
    float a0=b,a1=b,a2=b,a3=b;
    for (int k = 0; k < 512; ++k) {
      float w = cb_w1[(size_t)k*256 + o];
      a0 += comb[0][k]*w; a1 += comb[1][k]*w; a2 += comb[2][k]*w; a3 += comb[3][k]*w;
    }
    tmp[0][o]=fmaxf(a0,0.f); tmp[1][o]=fmaxf(a1,0.f);
    tmp[2][o]=fmaxf(a2,0.f); tmp[3][o]=fmaxf(a3,0.f);
  }
  __syncthreads();
  {
    float b = cb_b2[o];
    float c0=b,c1=b,c2=b,c3=b;
    for (int k = 0; k < 256; ++k) {
      float w = cb_w2[(size_t)k*256 + o];
      c0 += tmp[0][k]*w; c1 += tmp[1][k]*w; c2 += tmp[2][k]*w; c3 += tmp[3][k]*w;
    }
    out[(size_t)(g0+0)*OO + o] = c0;
    out[(size_t)(g0+1)*OO + o] = c1;
    out[(size_t)(g0+2)*OO + o] = c2;
    out[(size_t)(g0+3)*OO + o] = c3;
  }
}

extern "C" void kernel_launch(void* const* d_in, const int* in_sizes, int n_in,
                              void* d_out, int out_size, void* d_ws, size_t ws_size,
                              hipStream_t stream) {
  const float* x     = (const float*)d_in[0];
  const int*   adj   = (const int*)  d_in[1];
  const float* ef    = (const float*)d_in[2];
  const float* st_w  = (const float*)d_in[3];
  const float* st_b  = (const float*)d_in[4];
  const float* nt_w  = (const float*)d_in[5];
  const float* nt_b  = (const float*)d_in[6];
  const float* em_w1 = (const float*)d_in[7];
  const float* em_b1 = (const float*)d_in[8];
  const float* em_w2 = (const float*)d_in[9];
  const float* em_b2 = (const float*)d_in[10];
  const float* em_w3 = (const float*)d_in[11];
  const float* em_b3 = (const float*)d_in[12];
  const float* at_w1 = (const float*)d_in[13];
  const float* at_b1 = (const float*)d_in[14];
  const float* at_w2 = (const float*)d_in[15];
  const float* at_b2 = (const float*)d_in[16];
  const float* at_w3 = (const float*)d_in[17];
  const float* at_b3 = (const float*)d_in[18];
  const float* eg_w1 = (const float*)d_in[19];
  const float* eg_b1 = (const float*)d_in[20];
  const float* eg_w2 = (const float*)d_in[21];
  const float* eg_b2 = (const float*)d_in[22];
  const float* cb_w1 = (const float*)d_in[23];
  const float* cb_b1 = (const float*)d_in[24];
  const float* cb_w2 = (const float*)d_in[25];
  const float* cb_b2 = (const float*)d_in[26];
  float* ws  = (float*)d_ws;
  float* out = (float*)d_out;

  k_node<<<dim3(256), dim3(256), 0, stream>>>(x, st_w, st_b, nt_w, nt_b, at_w1, eg_w1, ws);
  k_edge<<<dim3(NN, BB), dim3(512), 0, stream>>>(adj, ef,
      em_w1, em_b1, em_w2, em_b2, em_w3, em_b3,
      at_w1, at_b1, at_w2, at_b2, at_w3, at_b3,
      eg_w1, eg_b1, eg_w2, eg_b2, ws);
  k_out<<<dim3(256), dim3(256), 0, stream>>>(cb_w1, cb_b1, cb_w2, cb_b2, ws, out);
}

// Round 2
// 385.477 us; speedup vs baseline: 2.1763x; 2.1763x over previous
//
#include <hip/hip_runtime.h>

#define BB 2
#define NN 512
#define CC 256
#define OO 256
#define EE 18
#define NT 512

// workspace layout (float offsets)
#define OFF_SF   0
#define OFF_NBR  (BB*NN*OO)
#define OFF_AI   (OFF_NBR + BB*NN*OO)
#define OFF_AJ   (OFF_AI + BB*NN*64)
#define OFF_EGX  (OFF_AJ + BB*NN*64)
#define OFF_MSG  (OFF_EGX + BB*NN*64)

typedef float f32x4 __attribute__((ext_vector_type(4)));
typedef __bf16 bf16x8 __attribute__((ext_vector_type(8)));

__device__ __forceinline__ unsigned short f2bf(float f) {
  unsigned u = __float_as_uint(f);
  u += 0x7fffu + ((u >> 16) & 1u);          // RNE
  return (unsigned short)(u >> 16);
}

__device__ __forceinline__ f32x4 mfma_bf16(uint4 a, uint4 b, f32x4 c) {
  return __builtin_amdgcn_mfma_f32_16x16x32_bf16(
      __builtin_bit_cast(bf16x8, a), __builtin_bit_cast(bf16x8, b), c, 0, 0, 0);
}

// stage W[K x L] (row-major) transposed into LDS as [L rows][128B], bf16,
// chunk-swizzled: byte = l*128 + (((k>>3) ^ (l&7))<<4) + (k&7)*2
template<int K, int L, int KV>
__device__ __forceinline__ void stage_wT(unsigned char* dst, const float* __restrict__ src, int t) {
  for (int idx = t; idx < K*L; idx += NT) {
    int k = idx / L, l = idx % L;
    float v = (k < KV) ? src[k*L + l] : 0.f;
    *(unsigned short*)(dst + l*128 + ((((k>>3) ^ (l&7))) << 4) + ((k&7) << 1)) = f2bf(v);
  }
}

// ---------------------------------------------------------------------------
// K1: per-node linear transforms.
// outputs: self_feat [B,N,256], nbr [B,N,256], a_i [B,N,64], a_j [B,N,64],
//          eg_x [B,N,64]
// ---------------------------------------------------------------------------
__global__ __launch_bounds__(256) void k_node(
    const float* __restrict__ x,
    const float* __restrict__ st_w, const float* __restrict__ st_b,
    const float* __restrict__ nt_w, const float* __restrict__ nt_b,
    const float* __restrict__ at_w1, const float* __restrict__ eg_w1,
    float* __restrict__ ws)
{
  __shared__ __align__(16) float xs[4*CC];
  const int t = threadIdx.x;
  const int g0 = blockIdx.x * 4;          // 4 nodes per block, 256 blocks
  for (int idx = t; idx < 4*CC; idx += 256) xs[idx] = x[(size_t)g0*CC + idx];
  __syncthreads();
  for (int col = t; col < 704; col += 256) {
    const float* W; int ldw;
    if (col < 256)      { W = st_w + col;                   ldw = 256; }
    else if (col < 512) { W = nt_w + (col - 256);           ldw = 256; }
    else if (col < 576) { W = at_w1 + (col - 512);          ldw = 64; }
    else if (col < 640) { W = at_w1 + 256*64 + (col - 576); ldw = 64; }
    else                { W = eg_w1 + (col - 640);          ldw = 64; }
    float a0=0.f, a1=0.f, a2=0.f, a3=0.f;
    #pragma unroll 8
    for (int k = 0; k < CC; ++k) {
      float w = W[(size_t)k*ldw];
      a0 += xs[k]*w; a1 += xs[CC+k]*w; a2 += xs[2*CC+k]*w; a3 += xs[3*CC+k]*w;
    }
    float av[4] = {a0,a1,a2,a3};
    #pragma unroll
    for (int m = 0; m < 4; ++m) {
      int g = g0 + m;
      if (col < 256)      ws[OFF_SF  + (size_t)g*OO + col]        = av[m] + st_b[col];
      else if (col < 512) ws[OFF_NBR + (size_t)g*OO + (col-256)]  = av[m] + nt_b[col-256];
      else if (col < 576) ws[OFF_AI  + (size_t)g*64 + (col-512)]  = av[m];
      else if (col < 640) ws[OFF_AJ  + (size_t)g*64 + (col-576)]  = av[m];
      else                ws[OFF_EGX + (size_t)g*64 + (col-640)]  = av[m];
    }
  }
}

// ---------------------------------------------------------------------------
// K2: fused per-row edge kernel, full-MFMA. 1 block per (i,b). 512 thr/8 waves.
// Wave w owns j-rows 64w..64w+63. All layers via mfma_f32_16x16x32_bf16 with
// activations bounced through one swizzled LDS buffer (wave-private rows).
// ---------------------------------------------------------------------------
__global__ __launch_bounds__(512, 1) void k_edge(
    const int*   __restrict__ adj,
    const float* __restrict__ ef_g,
    const float* __restrict__ em_w1g, const float* __restrict__ em_b1g,
    const float* __restrict__ em_w2g, const float* __restrict__ em_b2g,
    const float* __restrict__ em_w3g, const float* __restrict__ em_b3g,
    const float* __restrict__ at_w1g, const float* __restrict__ at_b1g,
    const float* __restrict__ at_w2g, const float* __restrict__ at_b2g,
    const float* __restrict__ at_w3g, const float* __restrict__ at_b3g,
    const float* __restrict__ eg_w1g, const float* __restrict__ eg_b1g,
    const float* __restrict__ eg_w2g, const float* __restrict__ eg_b2g,
    float* __restrict__ ws)
{
  __shared__ __align__(16) unsigned char s_act[512*128];   // 64 KB activation bounce
  __shared__ __align__(16) unsigned char s_em1T[64*128];
  __shared__ __align__(16) unsigned char s_em2T[64*128];
  __shared__ __align__(16) unsigned char s_em3T[32*128];
  __shared__ __align__(16) unsigned char s_at1T[64*128];
  __shared__ __align__(16) unsigned char s_at2T[32*128];
  __shared__ __align__(16) unsigned char s_eg1T[64*128];
  __shared__ __align__(16) unsigned char s_eg2T[256*128];
  __shared__ float s_bem1[64], s_bem2[64], s_bem3[32];
  __shared__ float s_t1init[64], s_bat2[32], s_w3[32];
  __shared__ float s_beg1[64], s_beg2[256];
  __shared__ float s_sc[512], s_maskf[512], s_red[8];
  __shared__ float s_msg[8][256];

  const int t = threadIdx.x;
  const int i = blockIdx.x, b = blockIdx.y;
  const int wid = t >> 6, lane = t & 63, l4 = lane >> 4, l16 = lane & 15;
  const int R = wid * 64;

  // ---------------- staging ----------------
  stage_wT<32, 64, 18>(s_em1T, em_w1g, t);
  stage_wT<64, 64, 64>(s_em2T, em_w2g, t);
  stage_wT<64, 32, 64>(s_em3T, em_w3g, t);
  stage_wT<32, 64, 32>(s_at1T, at_w1g + 512*64, t);
  stage_wT<64, 32, 64>(s_at2T, at_w2g, t);
  stage_wT<32, 64, 32>(s_eg1T, eg_w1g + 256*64, t);
  stage_wT<64, 256, 64>(s_eg2T, eg_w2g, t);

  if (t < 64) {
    s_bem1[t]   = em_b1g[t];
    s_bem2[t]   = em_b2g[t];
    s_t1init[t] = ws[OFF_AI + (size_t)(b*NN + i)*64 + t] + at_b1g[t];
    s_beg1[t]   = eg_b1g[t];
  } else if (t < 96)  { s_bem3[t-64]  = em_b3g[t-64]; }
  else if (t < 128)   { s_bat2[t-96]  = at_b2g[t-96]; }
  else if (t < 160)   { s_w3[t-128]   = at_w3g[t-128]; }
  if (t < 256) s_beg2[t] = eg_b2g[t];
  const float atb3 = at_b3g[0];

  s_maskf[t] = adj[(size_t)(b*NN + i)*NN + t] > 0 ? 1.f : 0.f;

  // stage ef row (pad 18 -> 32, bf16, swizzled)
  {
    const int j = t;
    const float* efp = ef_g + ((size_t)(b*NN + i)*NN + j) * EE;
    float e[32];
    #pragma unroll
    for (int k = 0; k < 9; ++k) { float2 v2 = *(const float2*)(efp + 2*k); e[2*k] = v2.x; e[2*k+1] = v2.y; }
    #pragma unroll
    for (int k = EE; k < 32; ++k) e[k] = 0.f;
    #pragma unroll
    for (int c = 0; c < 4; ++c) {
      unsigned u0 = (unsigned)f2bf(e[c*8+0]) | ((unsigned)f2bf(e[c*8+1]) << 16);
      unsigned u1 = (unsigned)f2bf(e[c*8+2]) | ((unsigned)f2bf(e[c*8+3]) << 16);
      unsigned u2 = (unsigned)f2bf(e[c*8+4]) | ((unsigned)f2bf(e[c*8+5]) << 16);
      unsigned u3 = (unsigned)f2bf(e[c*8+6]) | ((unsigned)f2bf(e[c*8+7]) << 16);
      *(uint4*)(s_act + j*128 + ((c ^ (j & 7)) << 4)) = make_uint4(u0,u1,u2,u3);
    }
  }
  __syncthreads();

  // fragment accessors
  auto loadA = [&](int rb, int f) -> uint4 {
    int rw = rb + l16;
    return *(const uint4*)(s_act + rw*128 + (((l4 + 4*f) ^ (rw & 7)) << 4));
  };
  auto loadB = [&](const unsigned char* w, int ct, int f) -> uint4 {
    int rw = ct*16 + l16;
    return *(const uint4*)(w + rw*128 + (((l4 + 4*f) ^ (rw & 7)) << 4));
  };
  auto storeCR = [&](int rb, int ct, const f32x4& c) {
    int col = ct*16 + l16;
    #pragma unroll
    for (int r = 0; r < 4; ++r) {
      int rw = rb + l4*4 + r;
      *(unsigned short*)(s_act + rw*128 + (((col >> 3) ^ (rw & 7)) << 4) + ((col & 7) << 1))
          = f2bf(fmaxf(c[r], 0.f));
    }
  };

  const float* ajbase  = ws + OFF_AJ  + (size_t)b*NN*64;
  const float* egbase  = ws + OFF_EGX + (size_t)b*NN*64;
  const float* nbrbase = ws + OFF_NBR + (size_t)b*NN*OO;

  uint4 peA[4];

  // ---- L1: ef(K32) -> h1(64) ----
  {
    uint4 B[4];
    #pragma unroll
    for (int ct = 0; ct < 4; ++ct) B[ct] = loadB(s_em1T, ct, 0);
    #pragma unroll
    for (int st = 0; st < 4; ++st) {
      int rb = R + st*16;
      uint4 a = loadA(rb, 0);
      #pragma unroll
      for (int ct = 0; ct < 4; ++ct) {
        float bz = s_bem1[ct*16 + l16];
        f32x4 c = {bz, bz, bz, bz};
        c = mfma_bf16(a, B[ct], c);
        storeCR(rb, ct, c);
      }
    }
  }
  // ---- L2: h1(K64) -> h2(64) ----
  {
    uint4 B[4][2];
    #pragma unroll
    for (int ct = 0; ct < 4; ++ct) { B[ct][0] = loadB(s_em2T, ct, 0); B[ct][1] = loadB(s_em2T, ct, 1); }
    #pragma unroll
    for (int st = 0; st < 4; ++st) {
      int rb = R + st*16;
      uint4 a0 = loadA(rb, 0), a1 = loadA(rb, 1);
      #pragma unroll
      for (int ct = 0; ct < 4; ++ct) {
        float bz = s_bem2[ct*16 + l16];
        f32x4 c = {bz, bz, bz, bz};
        c = mfma_bf16(a0, B[ct][0], c);
        c = mfma_bf16(a1, B[ct][1], c);
        storeCR(rb, ct, c);
      }
    }
  }
  // ---- L3: h2(K64) -> pe(32); keep pe in registers ----
  {
    uint4 B[2][2];
    #pragma unroll
    for (int ct = 0; ct < 2; ++ct) { B[ct][0] = loadB(s_em3T, ct, 0); B[ct][1] = loadB(s_em3T, ct, 1); }
    #pragma unroll
    for (int st = 0; st < 4; ++st) {
      int rb = R + st*16;
      uint4 a0 = loadA(rb, 0), a1 = loadA(rb, 1);
      #pragma unroll
      for (int ct = 0; ct < 2; ++ct) {
        float bz = s_bem3[ct*16 + l16];
        f32x4 c = {bz, bz, bz, bz};
        c = mfma_bf16(a0, B[ct][0], c);
        c = mfma_bf16(a1, B[ct][1], c);
        storeCR(rb, ct, c);
      }
      peA[st] = loadA(rb, 0);
    }
  }
  // ---- L4a: t1 = relu(a_i + a_j + b1 + pe @ at_w1e) ----
  {
    uint4 B[4];
    #pragma unroll
    for (int ct = 0; ct < 4; ++ct) B[ct] = loadB(s_at1T, ct, 0);
    #pragma unroll
    for (int st = 0; st < 4; ++st) {
      int rb = R + st*16;
      #pragma unroll
      for (int ct = 0; ct < 4; ++ct) {
        int col = ct*16 + l16;
        f32x4 c;
        #pragma unroll
        for (int r = 0; r < 4; ++r) {
          int rw = rb + l4*4 + r;
          c[r] = s_t1init[col] + ajbase[(size_t)rw*64 + col];
        }
        c = mfma_bf16(peA[st], B[ct], c);
        storeCR(rb, ct, c);
      }
    }
  }
  // ---- L5: t2 = relu(t1 @ at_w2 + b2); score = t2 . w3 + b3 (cross-lane) ----
  {
    uint4 B[2][2];
    #pragma unroll
    for (int ct = 0; ct < 2; ++ct) { B[ct][0] = loadB(s_at2T, ct, 0); B[ct][1] = loadB(s_at2T, ct, 1); }
    #pragma unroll
    for (int st = 0; st < 4; ++st) {
      int rb = R + st*16;
      uint4 a0 = loadA(rb, 0), a1 = loadA(rb, 1);
      float b0 = s_bat2[l16], b1v = s_bat2[16 + l16];
      f32x4 c0 = {b0, b0, b0, b0}, c1 = {b1v, b1v, b1v, b1v};
      c0 = mfma_bf16(a0, B[0][0], c0); c0 = mfma_bf16(a1, B[0][1], c0);
      c1 = mfma_bf16(a0, B[1][0], c1); c1 = mfma_bf16(a1, B[1][1], c1);
      float w3a = s_w3[l16], w3b = s_w3[16 + l16];
      #pragma unroll
      for (int r = 0; r < 4; ++r) {
        float val = fmaxf(c0[r], 0.f)*w3a + fmaxf(c1[r], 0.f)*w3b;
        val += __shfl_xor(val, 1); val += __shfl_xor(val, 2);
        val += __shfl_xor(val, 4); val += __shfl_xor(val, 8);
        if (l16 == 0) s_sc[rb + l4*4 + r] = val + atb3;
      }
    }
  }
  // ---- L4b: g1 = relu(eg_x_j + eg_b1 + pe @ eg_w1e) -> s_act ----
  {
    uint4 B[4];
    #pragma unroll
    for (int ct = 0; ct < 4; ++ct) B[ct] = loadB(s_eg1T, ct, 0);
    #pragma unroll
    for (int st = 0; st < 4; ++st) {
      int rb = R + st*16;
      #pragma unroll
      for (int ct = 0; ct < 4; ++ct) {
        int col = ct*16 + l16;
        f32x4 c;
        #pragma unroll
        for (int r = 0; r < 4; ++r) {
          int rw = rb + l4*4 + r;
          c[r] = s_beg1[col] + egbase[(size_t)rw*64 + col];
        }
        c = mfma_bf16(peA[st], B[ct], c);
        storeCR(rb, ct, c);
      }
    }
  }
  __syncthreads();   // scores + g1 visible

  // ---------------- masked softmax over j ----------------
  {
    float mf = s_maskf[t];
    float v  = mf > 0.f ? s_sc[t] : -1e9f;
    float m = v;
    #pragma unroll
    for (int d = 1; d < 64; d <<= 1) m = fmaxf(m, __shfl_xor(m, d));
    if (lane == 0) s_red[wid] = m;
    __syncthreads();
    float mx = s_red[0];
    #pragma unroll
    for (int w = 1; w < 8; ++w) mx = fmaxf(mx, s_red[w]);
    float p = mf > 0.f ? __expf(v - mx) : 0.f;
    float sm = p;
    #pragma unroll
    for (int d = 1; d < 64; d <<= 1) sm += __shfl_xor(sm, d);
    __syncthreads();
    if (lane == 0) s_red[wid] = sm;
    __syncthreads();
    float den = 0.f;
    #pragma unroll
    for (int w = 0; w < 8; ++w) den += s_red[w];
    float inv = den > 0.f ? 1.f/den : 0.f;
    s_sc[t] = p * inv;      // attn (normalized, masked-zero)
  }
  __syncthreads();

  // ---------------- L7: z = g1 @ eg_w2 + b2; msg += sigmoid(z)*attn*nbr ----
  {
    uint4 gA[4][2];
    #pragma unroll
    for (int st = 0; st < 4; ++st) { gA[st][0] = loadA(R + st*16, 0); gA[st][1] = loadA(R + st*16, 1); }
    for (int ct = 0; ct < 16; ++ct) {
      uint4 B0 = loadB(s_eg2T, ct, 0), B1 = loadB(s_eg2T, ct, 1);
      int col = ct*16 + l16;
      float bz = s_beg2[col];
      float msgp = 0.f;
      #pragma unroll
      for (int st = 0; st < 4; ++st) {
        f32x4 c = {bz, bz, bz, bz};
        c = mfma_bf16(gA[st][0], B0, c);
        c = mfma_bf16(gA[st][1], B1, c);
        int rb = R + st*16;
        #pragma unroll
        for (int r = 0; r < 4; ++r) {
          int rw = rb + l4*4 + r;
          float g = 1.f / (1.f + __expf(-c[r]));
          msgp += g * s_sc[rw] * nbrbase[(size_t)rw*OO + col];
        }
      }
      msgp += __shfl_xor(msgp, 16);
      msgp += __shfl_xor(msgp, 32);
      if (lane < 16) s_msg[wid][ct*16 + lane] = msgp;
    }
  }
  __syncthreads();
  if (t < 256) {
    float s = 0.f;
    #pragma unroll
    for (int w = 0; w < 8; ++w) s += s_msg[w][t];
    ws[OFF_MSG + (size_t)(b*NN + i)*OO + t] = s;
  }
}

// ---------------------------------------------------------------------------
// K3: out = relu([self_feat | msg] @ cb_w1 + cb_b1) @ cb_w2 + cb_b2
// ---------------------------------------------------------------------------
__global__ __launch_bounds__(256) void k_out(
    const float* __restrict__ cb_w1, const float* __restrict__ cb_b1,
    const float* __restrict__ cb_w2, const float* __restrict__ cb_b2,
    const float* __restrict__ ws, float* __restrict__ out)
{
  __shared__ __align__(16) float comb[4][512];
  __shared__ __align__(16) float tmp[4][256];
  const int t = threadIdx.x;
  const int g0 = blockIdx.x * 4;
  for (int idx = t; idx < 4*256; idx += 256) {
    int mm = idx >> 8, c = idx & 255;
    comb[mm][c]       = ws[OFF_SF  + (size_t)(g0+mm)*OO + c];
    comb[mm][256 + c] = ws[OFF_MSG + (size_t)(g0+mm)*OO + c];
  }
  __syncthreads();
  const int o = t;
  {
    float b = cb_b1[o];
    float a0=b,a1=b,a2=b,a3=b;
    for (int k = 0; k < 512; ++k) {
      float w = cb_w1[(size_t)k*256 + o];
      a0 += comb[0][k]*w; a1 += comb[1][k]*w; a2 += comb[2][k]*w; a3 += comb[3][k]*w;
    }
    tmp[0][o]=fmaxf(a0,0.f); tmp[1][o]=fmaxf(a1,0.f);
    tmp[2][o]=fmaxf(a2,0.f); tmp[3][o]=fmaxf(a3,0.f);
  }
  __syncthreads();
  {
    float b = cb_b2[o];
    float c0=b,c1=b,c2=b,c3=b;
    for (int k = 0; k < 256; ++k) {
      float w = cb_w2[(size_t)k*256 + o];
      c0 += tmp[0][k]*w; c1 += tmp[1][k]*w; c2 += tmp[2][k]*w; c3 += tmp[3][k]*w;
    }
    out[(size_t)(g0+0)*OO + o] = c0;
    out[(size_t)(g0+1)*OO + o] = c1;
    out[(size_t)(g0+2)*OO + o] = c2;
    out[(size_t)(g0+3)*OO + o] = c3;
  }
}

extern "C" void kernel_launch(void* const* d_in, const int* in_sizes, int n_in,
                              void* d_out, int out_size, void* d_ws, size_t ws_size,
                              hipStream_t stream) {
  const float* x     = (const float*)d_in[0];
  const int*   adj   = (const int*)  d_in[1];
  const float* ef    = (const float*)d_in[2];
  const float* st_w  = (const float*)d_in[3];
  const float* st_b  = (const float*)d_in[4];
  const float* nt_w  = (const float*)d_in[5];
  const float* nt_b  = (const float*)d_in[6];
  const float* em_w1 = (const float*)d_in[7];
  const float* em_b1 = (const float*)d_in[8];
  const float* em_w2 = (const float*)d_in[9];
  const float* em_b2 = (const float*)d_in[10];
  const float* em_w3 = (const float*)d_in[11];
  const float* em_b3 = (const float*)d_in[12];
  const float* at_w1 = (const float*)d_in[13];
  const float* at_b1 = (const float*)d_in[14];
  const float* at_w2 = (const float*)d_in[15];
  const float* at_b2 = (const float*)d_in[16];
  const float* at_w3 = (const float*)d_in[17];
  const float* at_b3 = (const float*)d_in[18];
  const float* eg_w1 = (const float*)d_in[19];
  const float* eg_b1 = (const float*)d_in[20];
  const float* eg_w2 = (const float*)d_in[21];
  const float* eg_b2 = (const float*)d_in[22];
  const float* cb_w1 = (const float*)d_in[23];
  const float* cb_b1 = (const float*)d_in[24];
  const float* cb_w2 = (const float*)d_in[25];
  const float* cb_b2 = (const float*)d_in[26];
  float* ws  = (float*)d_ws;
  float* out = (float*)d_out;

  k_node<<<dim3(256), dim3(256), 0, stream>>>(x, st_w, st_b, nt_w, nt_b, at_w1, eg_w1, ws);
  k_edge<<<dim3(NN, BB), dim3(512), 0, stream>>>(adj, ef,
      em_w1, em_b1, em_w2, em_b2, em_w3, em_b3,
      at_w1, at_b1, at_w2, at_b2, at_w3, at_b3,
      eg_w1, eg_b1, eg_w2, eg_b2, ws);
  k_out<<<dim3(256), dim3(256), 0, stream>>>(cb_w1, cb_b1, cb_w2, cb_b2, ws, out);
}

// Round 3
// 196.566 us; speedup vs baseline: 4.2678x; 1.9611x over previous
//
#include <hip/hip_runtime.h>

#define BB 2
#define NN 512
#define CC 256
#define OO 256
#define EE 18
#define NT 512

// workspace layout (float offsets)
#define OFF_SF   0
#define OFF_NBR  (BB*NN*OO)
#define OFF_AI   (OFF_NBR + BB*NN*OO)
#define OFF_AJ   (OFF_AI + BB*NN*64)
#define OFF_EGX  (OFF_AJ + BB*NN*64)
#define OFF_MSG  (OFF_EGX + BB*NN*64)
// aliased weight-staging regions (lifetime-disjoint):
// WN lives in MSG region: written by prep_node, read by k_node, clobbered by k_edge.
// W1/W2 live in AI/AJ regions: written by prep_out AFTER k_edge, read by k_out.
#define OFF_WN   OFF_MSG
#define OFF_W1   OFF_AI
#define OFF_W2   OFF_AJ

typedef float f32x4 __attribute__((ext_vector_type(4)));
typedef __bf16 bf16x8 __attribute__((ext_vector_type(8)));

__device__ __forceinline__ unsigned short f2bf(float f) {
  unsigned u = __float_as_uint(f);
  u += 0x7fffu + ((u >> 16) & 1u);          // RNE
  return (unsigned short)(u >> 16);
}
__device__ __forceinline__ unsigned pk2(float a, float b) {
  return (unsigned)f2bf(a) | ((unsigned)f2bf(b) << 16);
}
__device__ __forceinline__ int swzc(int chunk, int row) {
  return (chunk & ~7) | ((chunk ^ row) & 7);
}

__device__ __forceinline__ f32x4 mfma_bf16(uint4 a, uint4 b, f32x4 c) {
  return __builtin_amdgcn_mfma_f32_16x16x32_bf16(
      __builtin_bit_cast(bf16x8, a), __builtin_bit_cast(bf16x8, b), c, 0, 0, 0);
}

// stage W[K x L] (row-major) transposed into LDS as [L rows][128B], bf16,
// chunk-swizzled: byte = l*128 + swzc(k>>3, l)*16 + (k&7)*2
template<int K, int L, int KV>
__device__ __forceinline__ void stage_wT(unsigned char* dst, const float* __restrict__ src, int t) {
  for (int idx = t; idx < K*L; idx += NT) {
    int k = idx / L, l = idx % L;
    float v = (k < KV) ? src[k*L + l] : 0.f;
    *(unsigned short*)(dst + l*128 + ((((k>>3) ^ (l&7))) << 4) + ((k&7) << 1)) = f2bf(v);
  }
}

// ---------------------------------------------------------------------------
// prep_node: gather node-transform weights into Wnode [704 cols][256 k] bf16,
// swizzled for direct B-fragment loads. 88 blocks x 256 thr; thread = (col, chunk).
// ---------------------------------------------------------------------------
__global__ __launch_bounds__(256) void k_prep_node(
    const float* __restrict__ st_w, const float* __restrict__ nt_w,
    const float* __restrict__ at_w1, const float* __restrict__ eg_w1,
    float* __restrict__ ws)
{
  unsigned char* dst = (unsigned char*)(ws + OFF_WN);
  int idx = blockIdx.x * 256 + threadIdx.x;       // 704*32 = 22528
  int col = idx >> 5, ch = idx & 31;
  const float* src; int ld, c;
  if (col < 256)      { src = st_w;           ld = 256; c = col; }
  else if (col < 512) { src = nt_w;           ld = 256; c = col - 256; }
  else if (col < 576) { src = at_w1;          ld = 64;  c = col - 512; }
  else if (col < 640) { src = at_w1 + 256*64; ld = 64;  c = col - 576; }
  else                { src = eg_w1;          ld = 64;  c = col - 640; }
  float e[8];
  #pragma unroll
  for (int q = 0; q < 8; ++q) e[q] = src[(size_t)(ch*8+q)*ld + c];
  uint4 v = make_uint4(pk2(e[0],e[1]), pk2(e[2],e[3]), pk2(e[4],e[5]), pk2(e[6],e[7]));
  *(uint4*)(dst + (size_t)col*512 + swzc(ch, col)*16) = v;
}

// ---------------------------------------------------------------------------
// prep_out: cb_w1 [512][256] -> W1 [256 cols][512 k] bf16; cb_w2 [256][256] -> W2.
// Runs AFTER k_edge (aliases AI/AJ). 96 blocks.
// ---------------------------------------------------------------------------
__global__ __launch_bounds__(256) void k_prep_out(
    const float* __restrict__ cb_w1, const float* __restrict__ cb_w2,
    float* __restrict__ ws)
{
  int bid = blockIdx.x;
  if (bid < 64) {
    unsigned char* dst = (unsigned char*)(ws + OFF_W1);
    int idx = bid * 256 + threadIdx.x;            // 256*64
    int col = idx >> 6, ch = idx & 63;
    float e[8];
    #pragma unroll
    for (int q = 0; q < 8; ++q) e[q] = cb_w1[(size_t)(ch*8+q)*256 + col];
    uint4 v = make_uint4(pk2(e[0],e[1]), pk2(e[2],e[3]), pk2(e[4],e[5]), pk2(e[6],e[7]));
    *(uint4*)(dst + (size_t)col*1024 + swzc(ch, col)*16) = v;
  } else {
    unsigned char* dst = (unsigned char*)(ws + OFF_W2);
    int idx = (bid - 64) * 256 + threadIdx.x;     // 256*32
    int col = idx >> 5, ch = idx & 31;
    float e[8];
    #pragma unroll
    for (int q = 0; q < 8; ++q) e[q] = cb_w2[(size_t)(ch*8+q)*256 + col];
    uint4 v = make_uint4(pk2(e[0],e[1]), pk2(e[2],e[3]), pk2(e[4],e[5]), pk2(e[6],e[7]));
    *(uint4*)(dst + (size_t)col*512 + swzc(ch, col)*16) = v;
  }
}

// ---------------------------------------------------------------------------
// k_node (MFMA): C[1024 x 704] = x[1024 x 256] @ Wnode. Tile 64M x 64N,
// grid (11 N-tiles, 16 M-tiles). A staged in LDS bf16; B streamed from Wnode.
// Epilogue routes columns to SF/NBR/AI/AJ/EGX with biases.
// ---------------------------------------------------------------------------
__global__ __launch_bounds__(256) void k_node(
    const float* __restrict__ x,
    const float* __restrict__ st_b, const float* __restrict__ nt_b,
    float* __restrict__ ws)
{
  __shared__ __align__(16) unsigned char sA[64*512];   // 32 KB
  const int t = threadIdx.x;
  const int c0 = blockIdx.x * 64, g0 = blockIdx.y * 64;

  for (int idx = t; idx < 64*64; idx += 256) {
    int row = idx >> 6, kq = idx & 63;       // kq: group of 4 k
    float4 v = *(const float4*)(x + (size_t)(g0 + row)*CC + kq*4);
    uint2 p; p.x = pk2(v.x, v.y); p.y = pk2(v.z, v.w);
    *(uint2*)(sA + row*512 + swzc(kq >> 1, row)*16 + (kq & 1)*8) = p;
  }
  __syncthreads();

  const int wid = t >> 6, lane = t & 63, l4 = lane >> 4, l16 = lane & 15;
  const unsigned char* WN = (const unsigned char*)(ws + OFF_WN);

  uint4 af[8];
  {
    int row = wid*16 + l16;
    #pragma unroll
    for (int f = 0; f < 8; ++f)
      af[f] = *(const uint4*)(sA + row*512 + swzc(l4 + 4*f, row)*16);
  }

  #pragma unroll
  for (int ct = 0; ct < 4; ++ct) {
    int gcol = c0 + ct*16 + l16;
    f32x4 acc = {0.f, 0.f, 0.f, 0.f};
    #pragma unroll
    for (int f = 0; f < 8; ++f) {
      uint4 bfr = *(const uint4*)(WN + (size_t)gcol*512 + swzc(l4 + 4*f, gcol)*16);
      acc = mfma_bf16(af[f], bfr, acc);
    }
    int gr0 = g0 + wid*16 + l4*4;
    if (gcol < 256) {
      float bz = st_b[gcol];
      #pragma unroll
      for (int r = 0; r < 4; ++r) ws[OFF_SF + (size_t)(gr0+r)*OO + gcol] = acc[r] + bz;
    } else if (gcol < 512) {
      float bz = nt_b[gcol - 256];
      #pragma unroll
      for (int r = 0; r < 4; ++r) ws[OFF_NBR + (size_t)(gr0+r)*OO + (gcol-256)] = acc[r] + bz;
    } else if (gcol < 576) {
      #pragma unroll
      for (int r = 0; r < 4; ++r) ws[OFF_AI + (size_t)(gr0+r)*64 + (gcol-512)] = acc[r];
    } else if (gcol < 640) {
      #pragma unroll
      for (int r = 0; r < 4; ++r) ws[OFF_AJ + (size_t)(gr0+r)*64 + (gcol-576)] = acc[r];
    } else {
      #pragma unroll
      for (int r = 0; r < 4; ++r) ws[OFF_EGX + (size_t)(gr0+r)*64 + (gcol-640)] = acc[r];
    }
  }
}

// ---------------------------------------------------------------------------
// K2: fused per-row edge kernel, full-MFMA. 1 block per (i,b). 512 thr/8 waves.
// (unchanged from round 2)
// ---------------------------------------------------------------------------
__global__ __launch_bounds__(512, 1) void k_edge(
    const int*   __restrict__ adj,
    const float* __restrict__ ef_g,
    const float* __restrict__ em_w1g, const float* __restrict__ em_b1g,
    const float* __restrict__ em_w2g, const float* __restrict__ em_b2g,
    const float* __restrict__ em_w3g, const float* __restrict__ em_b3g,
    const float* __restrict__ at_w1g, const float* __restrict__ at_b1g,
    const float* __restrict__ at_w2g, const float* __restrict__ at_b2g,
    const float* __restrict__ at_w3g, const float* __restrict__ at_b3g,
    const float* __restrict__ eg_w1g, const float* __restrict__ eg_b1g,
    const float* __restrict__ eg_w2g, const float* __restrict__ eg_b2g,
    float* __restrict__ ws)
{
  __shared__ __align__(16) unsigned char s_act[512*128];   // 64 KB activation bounce
  __shared__ __align__(16) unsigned char s_em1T[64*128];
  __shared__ __align__(16) unsigned char s_em2T[64*128];
  __shared__ __align__(16) unsigned char s_em3T[32*128];
  __shared__ __align__(16) unsigned char s_at1T[64*128];
  __shared__ __align__(16) unsigned char s_at2T[32*128];
  __shared__ __align__(16) unsigned char s_eg1T[64*128];
  __shared__ __align__(16) unsigned char s_eg2T[256*128];
  __shared__ float s_bem1[64], s_bem2[64], s_bem3[32];
  __shared__ float s_t1init[64], s_bat2[32], s_w3[32];
  __shared__ float s_beg1[64], s_beg2[256];
  __shared__ float s_sc[512], s_maskf[512], s_red[8];
  __shared__ float s_msg[8][256];

  const int t = threadIdx.x;
  const int i = blockIdx.x, b = blockIdx.y;
  const int wid = t >> 6, lane = t & 63, l4 = lane >> 4, l16 = lane & 15;
  const int R = wid * 64;

  stage_wT<32, 64, 18>(s_em1T, em_w1g, t);
  stage_wT<64, 64, 64>(s_em2T, em_w2g, t);
  stage_wT<64, 32, 64>(s_em3T, em_w3g, t);
  stage_wT<32, 64, 32>(s_at1T, at_w1g + 512*64, t);
  stage_wT<64, 32, 64>(s_at2T, at_w2g, t);
  stage_wT<32, 64, 32>(s_eg1T, eg_w1g + 256*64, t);
  stage_wT<64, 256, 64>(s_eg2T, eg_w2g, t);

  if (t < 64) {
    s_bem1[t]   = em_b1g[t];
    s_bem2[t]   = em_b2g[t];
    s_t1init[t] = ws[OFF_AI + (size_t)(b*NN + i)*64 + t] + at_b1g[t];
    s_beg1[t]   = eg_b1g[t];
  } else if (t < 96)  { s_bem3[t-64]  = em_b3g[t-64]; }
  else if (t < 128)   { s_bat2[t-96]  = at_b2g[t-96]; }
  else if (t < 160)   { s_w3[t-128]   = at_w3g[t-128]; }
  if (t < 256) s_beg2[t] = eg_b2g[t];
  const float atb3 = at_b3g[0];

  s_maskf[t] = adj[(size_t)(b*NN + i)*NN + t] > 0 ? 1.f : 0.f;

  {
    const int j = t;
    const float* efp = ef_g + ((size_t)(b*NN + i)*NN + j) * EE;
    float e[32];
    #pragma unroll
    for (int k = 0; k < 9; ++k) { float2 v2 = *(const float2*)(efp + 2*k); e[2*k] = v2.x; e[2*k+1] = v2.y; }
    #pragma unroll
    for (int k = EE; k < 32; ++k) e[k] = 0.f;
    #pragma unroll
    for (int c = 0; c < 4; ++c) {
      uint4 u = make_uint4(pk2(e[c*8+0],e[c*8+1]), pk2(e[c*8+2],e[c*8+3]),
                           pk2(e[c*8+4],e[c*8+5]), pk2(e[c*8+6],e[c*8+7]));
      *(uint4*)(s_act + j*128 + ((c ^ (j & 7)) << 4)) = u;
    }
  }
  __syncthreads();

  auto loadA = [&](int rb, int f) -> uint4 {
    int rw = rb + l16;
    return *(const uint4*)(s_act + rw*128 + (((l4 + 4*f) ^ (rw & 7)) << 4));
  };
  auto loadB = [&](const unsigned char* w, int ct, int f) -> uint4 {
    int rw = ct*16 + l16;
    return *(const uint4*)(w + rw*128 + (((l4 + 4*f) ^ (rw & 7)) << 4));
  };
  auto storeCR = [&](int rb, int ct, const f32x4& c) {
    int col = ct*16 + l16;
    #pragma unroll
    for (int r = 0; r < 4; ++r) {
      int rw = rb + l4*4 + r;
      *(unsigned short*)(s_act + rw*128 + (((col >> 3) ^ (rw & 7)) << 4) + ((col & 7) << 1))
          = f2bf(fmaxf(c[r], 0.f));
    }
  };

  const float* ajbase  = ws + OFF_AJ  + (size_t)b*NN*64;
  const float* egbase  = ws + OFF_EGX + (size_t)b*NN*64;
  const float* nbrbase = ws + OFF_NBR + (size_t)b*NN*OO;

  uint4 peA[4];

  {
    uint4 B[4];
    #pragma unroll
    for (int ct = 0; ct < 4; ++ct) B[ct] = loadB(s_em1T, ct, 0);
    #pragma unroll
    for (int st = 0; st < 4; ++st) {
      int rb = R + st*16;
      uint4 a = loadA(rb, 0);
      #pragma unroll
      for (int ct = 0; ct < 4; ++ct) {
        float bz = s_bem1[ct*16 + l16];
        f32x4 c = {bz, bz, bz, bz};
        c = mfma_bf16(a, B[ct], c);
        storeCR(rb, ct, c);
      }
    }
  }
  {
    uint4 B[4][2];
    #pragma unroll
    for (int ct = 0; ct < 4; ++ct) { B[ct][0] = loadB(s_em2T, ct, 0); B[ct][1] = loadB(s_em2T, ct, 1); }
    #pragma unroll
    for (int st = 0; st < 4; ++st) {
      int rb = R + st*16;
      uint4 a0 = loadA(rb, 0), a1 = loadA(rb, 1);
      #pragma unroll
      for (int ct = 0; ct < 4; ++ct) {
        float bz = s_bem2[ct*16 + l16];
        f32x4 c = {bz, bz, bz, bz};
        c = mfma_bf16(a0, B[ct][0], c);
        c = mfma_bf16(a1, B[ct][1], c);
        storeCR(rb, ct, c);
      }
    }
  }
  {
    uint4 B[2][2];
    #pragma unroll
    for (int ct = 0; ct < 2; ++ct) { B[ct][0] = loadB(s_em3T, ct, 0); B[ct][1] = loadB(s_em3T, ct, 1); }
    #pragma unroll
    for (int st = 0; st < 4; ++st) {
      int rb = R + st*16;
      uint4 a0 = loadA(rb, 0), a1 = loadA(rb, 1);
      #pragma unroll
      for (int ct = 0; ct < 2; ++ct) {
        float bz = s_bem3[ct*16 + l16];
        f32x4 c = {bz, bz, bz, bz};
        c = mfma_bf16(a0, B[ct][0], c);
        c = mfma_bf16(a1, B[ct][1], c);
        storeCR(rb, ct, c);
      }
      peA[st] = loadA(rb, 0);
    }
  }
  {
    uint4 B[4];
    #pragma unroll
    for (int ct = 0; ct < 4; ++ct) B[ct] = loadB(s_at1T, ct, 0);
    #pragma unroll
    for (int st = 0; st < 4; ++st) {
      int rb = R + st*16;
      #pragma unroll
      for (int ct = 0; ct < 4; ++ct) {
        int col = ct*16 + l16;
        f32x4 c;
        #pragma unroll
        for (int r = 0; r < 4; ++r) {
          int rw = rb + l4*4 + r;
          c[r] = s_t1init[col] + ajbase[(size_t)rw*64 + col];
        }
        c = mfma_bf16(peA[st], B[ct], c);
        storeCR(rb, ct, c);
      }
    }
  }
  {
    uint4 B[2][2];
    #pragma unroll
    for (int ct = 0; ct < 2; ++ct) { B[ct][0] = loadB(s_at2T, ct, 0); B[ct][1] = loadB(s_at2T, ct, 1); }
    #pragma unroll
    for (int st = 0; st < 4; ++st) {
      int rb = R + st*16;
      uint4 a0 = loadA(rb, 0), a1 = loadA(rb, 1);
      float b0 = s_bat2[l16], b1v = s_bat2[16 + l16];
      f32x4 c0 = {b0, b0, b0, b0}, c1 = {b1v, b1v, b1v, b1v};
      c0 = mfma_bf16(a0, B[0][0], c0); c0 = mfma_bf16(a1, B[0][1], c0);
      c1 = mfma_bf16(a0, B[1][0], c1); c1 = mfma_bf16(a1, B[1][1], c1);
      float w3a = s_w3[l16], w3b = s_w3[16 + l16];
      #pragma unroll
      for (int r = 0; r < 4; ++r) {
        float val = fmaxf(c0[r], 0.f)*w3a + fmaxf(c1[r], 0.f)*w3b;
        val += __shfl_xor(val, 1); val += __shfl_xor(val, 2);
        val += __shfl_xor(val, 4); val += __shfl_xor(val, 8);
        if (l16 == 0) s_sc[rb + l4*4 + r] = val + atb3;
      }
    }
  }
  {
    uint4 B[4];
    #pragma unroll
    for (int ct = 0; ct < 4; ++ct) B[ct] = loadB(s_eg1T, ct, 0);
    #pragma unroll
    for (int st = 0; st < 4; ++st) {
      int rb = R + st*16;
      #pragma unroll
      for (int ct = 0; ct < 4; ++ct) {
        int col = ct*16 + l16;
        f32x4 c;
        #pragma unroll
        for (int r = 0; r < 4; ++r) {
          int rw = rb + l4*4 + r;
          c[r] = s_beg1[col] + egbase[(size_t)rw*64 + col];
        }
        c = mfma_bf16(peA[st], B[ct], c);
        storeCR(rb, ct, c);
      }
    }
  }
  __syncthreads();

  {
    float mf = s_maskf[t];
    float v  = mf > 0.f ? s_sc[t] : -1e9f;
    float m = v;
    #pragma unroll
    for (int d = 1; d < 64; d <<= 1) m = fmaxf(m, __shfl_xor(m, d));
    if (lane == 0) s_red[wid] = m;
    __syncthreads();
    float mx = s_red[0];
    #pragma unroll
    for (int w = 1; w < 8; ++w) mx = fmaxf(mx, s_red[w]);
    float p = mf > 0.f ? __expf(v - mx) : 0.f;
    float sm = p;
    #pragma unroll
    for (int d = 1; d < 64; d <<= 1) sm += __shfl_xor(sm, d);
    __syncthreads();
    if (lane == 0) s_red[wid] = sm;
    __syncthreads();
    float den = 0.f;
    #pragma unroll
    for (int w = 0; w < 8; ++w) den += s_red[w];
    float inv = den > 0.f ? 1.f/den : 0.f;
    s_sc[t] = p * inv;
  }
  __syncthreads();

  {
    uint4 gA[4][2];
    #pragma unroll
    for (int st = 0; st < 4; ++st) { gA[st][0] = loadA(R + st*16, 0); gA[st][1] = loadA(R + st*16, 1); }
    for (int ct = 0; ct < 16; ++ct) {
      uint4 B0 = loadB(s_eg2T, ct, 0), B1 = loadB(s_eg2T, ct, 1);
      int col = ct*16 + l16;
      float bz = s_beg2[col];
      float msgp = 0.f;
      #pragma unroll
      for (int st = 0; st < 4; ++st) {
        f32x4 c = {bz, bz, bz, bz};
        c = mfma_bf16(gA[st][0], B0, c);
        c = mfma_bf16(gA[st][1], B1, c);
        int rb = R + st*16;
        #pragma unroll
        for (int r = 0; r < 4; ++r) {
          int rw = rb + l4*4 + r;
          float g = 1.f / (1.f + __expf(-c[r]));
          msgp += g * s_sc[rw] * nbrbase[(size_t)rw*OO + col];
        }
      }
      msgp += __shfl_xor(msgp, 16);
      msgp += __shfl_xor(msgp, 32);
      if (lane < 16) s_msg[wid][ct*16 + lane] = msgp;
    }
  }
  __syncthreads();
  if (t < 256) {
    float s = 0.f;
    #pragma unroll
    for (int w = 0; w < 8; ++w) s += s_msg[w][t];
    ws[OFF_MSG + (size_t)(b*NN + i)*OO + t] = s;
  }
}

// ---------------------------------------------------------------------------
// k_out (MFMA): 64 blocks x 16 rows. Phase1: comb[16x512] @ W1 -> tmp (relu, LDS).
// Phase2: tmp[16x256] @ W2 -> out. B streamed from prep'd bf16 global.
// ---------------------------------------------------------------------------
__global__ __launch_bounds__(256) void k_out(
    const float* __restrict__ cb_b1, const float* __restrict__ cb_b2,
    const float* __restrict__ ws, float* __restrict__ out)
{
  __shared__ __align__(16) unsigned char sA[16*1024];   // comb bf16, 16 KB
  __shared__ __align__(16) unsigned char sT[16*512];    // tmp bf16, 8 KB
  const int t = threadIdx.x;
  const int g0 = blockIdx.x * 16;

  for (int idx = t; idx < 16*128; idx += 256) {
    int row = idx >> 7, kq = idx & 127;
    const float* src = (kq < 64)
        ? ws + OFF_SF  + (size_t)(g0 + row)*OO + kq*4
        : ws + OFF_MSG + (size_t)(g0 + row)*OO + (kq - 64)*4;
    float4 v = *(const float4*)src;
    uint2 p; p.x = pk2(v.x, v.y); p.y = pk2(v.z, v.w);
    *(uint2*)(sA + row*1024 + swzc(kq >> 1, row)*16 + (kq & 1)*8) = p;
  }
  __syncthreads();

  const int wid = t >> 6, lane = t & 63, l4 = lane >> 4, l16 = lane & 15;
  const unsigned char* W1 = (const unsigned char*)(ws + OFF_W1);
  const unsigned char* W2 = (const unsigned char*)(ws + OFF_W2);

  // phase 1: K=512, each wave 4 col-tiles
  {
    uint4 af[16];
    #pragma unroll
    for (int f = 0; f < 16; ++f)
      af[f] = *(const uint4*)(sA + l16*1024 + swzc(l4 + 4*f, l16)*16);
    #pragma unroll
    for (int c = 0; c < 4; ++c) {
      int col = wid*64 + c*16 + l16;
      float bz = cb_b1[col];
      f32x4 acc = {bz, bz, bz, bz};
      #pragma unroll
      for (int f = 0; f < 16; ++f) {
        uint4 bfr = *(const uint4*)(W1 + (size_t)col*1024 + swzc(l4 + 4*f, col)*16);
        acc = mfma_bf16(af[f], bfr, acc);
      }
      #pragma unroll
      for (int r = 0; r < 4; ++r) {
        int row = l4*4 + r;
        *(unsigned short*)(sT + row*512 + swzc(col >> 3, row)*16 + (col & 7)*2)
            = f2bf(fmaxf(acc[r], 0.f));
      }
    }
  }
  __syncthreads();

  // phase 2: K=256
  {
    uint4 tf[8];
    #pragma unroll
    for (int f = 0; f < 8; ++f)
      tf[f] = *(const uint4*)(sT + l16*512 + swzc(l4 + 4*f, l16)*16);
    #pragma unroll
    for (int c = 0; c < 4; ++c) {
      int col = wid*64 + c*16 + l16;
      float bz = cb_b2[col];
      f32x4 acc = {bz, bz, bz, bz};
      #pragma unroll
      for (int f = 0; f < 8; ++f) {
        uint4 bfr = *(const uint4*)(W2 + (size_t)col*512 + swzc(l4 + 4*f, col)*16);
        acc = mfma_bf16(tf[f], bfr, acc);
      }
      #pragma unroll
      for (int r = 0; r < 4; ++r)
        out[(size_t)(g0 + l4*4 + r)*OO + col] = acc[r];
    }
  }
}

extern "C" void kernel_launch(void* const* d_in, const int* in_sizes, int n_in,
                              void* d_out, int out_size, void* d_ws, size_t ws_size,
                              hipStream_t stream) {
  const float* x     = (const float*)d_in[0];
  const int*   adj   = (const int*)  d_in[1];
  const float* ef    = (const float*)d_in[2];
  const float* st_w  = (const float*)d_in[3];
  const float* st_b  = (const float*)d_in[4];
  const float* nt_w  = (const float*)d_in[5];
  const float* nt_b  = (const float*)d_in[6];
  const float* em_w1 = (const float*)d_in[7];
  const float* em_b1 = (const float*)d_in[8];
  const float* em_w2 = (const float*)d_in[9];
  const float* em_b2 = (const float*)d_in[10];
  const float* em_w3 = (const float*)d_in[11];
  const float* em_b3 = (const float*)d_in[12];
  const float* at_w1 = (const float*)d_in[13];
  const float* at_b1 = (const float*)d_in[14];
  const float* at_w2 = (const float*)d_in[15];
  const float* at_b2 = (const float*)d_in[16];
  const float* at_w3 = (const float*)d_in[17];
  const float* at_b3 = (const float*)d_in[18];
  const float* eg_w1 = (const float*)d_in[19];
  const float* eg_b1 = (const float*)d_in[20];
  const float* eg_w2 = (const float*)d_in[21];
  const float* eg_b2 = (const float*)d_in[22];
  const float* cb_w1 = (const float*)d_in[23];
  const float* cb_b1 = (const float*)d_in[24];
  const float* cb_w2 = (const float*)d_in[25];
  const float* cb_b2 = (const float*)d_in[26];
  float* ws  = (float*)d_ws;
  float* out = (float*)d_out;

  k_prep_node<<<dim3(88), dim3(256), 0, stream>>>(st_w, nt_w, at_w1, eg_w1, ws);
  k_node<<<dim3(11, 16), dim3(256), 0, stream>>>(x, st_b, nt_b, ws);
  k_edge<<<dim3(NN, BB), dim3(512), 0, stream>>>(adj, ef,
      em_w1, em_b1, em_w2, em_b2, em_w3, em_b3,
      at_w1, at_b1, at_w2, at_b2, at_w3, at_b3,
      eg_w1, eg_b1, eg_w2, eg_b2, ws);
  k_prep_out<<<dim3(96), dim3(256), 0, stream>>>(cb_w1, cb_w2, ws);
  k_out<<<dim3(64), dim3(256), 0, stream>>>(cb_b1, cb_b2, ws, out);
}

// Round 4
// 185.421 us; speedup vs baseline: 4.5243x; 1.0601x over previous
//
#include <hip/hip_runtime.h>

#define BB 2
#define NN 512
#define CC 256
#define OO 256
#define EE 18

// workspace layout (float offsets)
#define OFF_SF   0
#define OFF_NBR  (BB*NN*OO)
#define OFF_AI   (OFF_NBR + BB*NN*OO)
#define OFF_AJ   (OFF_AI + BB*NN*64)
#define OFF_EGX  (OFF_AJ + BB*NN*64)
#define OFF_MSG  (OFF_EGX + BB*NN*64)
// NOTE: NBR/AJ/EGX are stored TRANSPOSED: [b][col][row]
// aliased weight-staging regions (lifetime-disjoint):
// WN in MSG region (prep_node -> k_node, clobbered later by k_edge MSG writes).
// W1/W2 in AI/AJ regions (prep_out runs AFTER k_edge).
// Edge-weight image lives in d_out (dead until k_out overwrites it).
#define OFF_WN   OFF_MSG
#define OFF_W1   OFF_AI
#define OFF_W2   OFF_AJ

typedef float f32x4 __attribute__((ext_vector_type(4)));
typedef __bf16 bf16x8 __attribute__((ext_vector_type(8)));

__device__ __forceinline__ unsigned short f2bf(float f) {
  unsigned u = __float_as_uint(f);
  u += 0x7fffu + ((u >> 16) & 1u);          // RNE
  return (unsigned short)(u >> 16);
}
__device__ __forceinline__ unsigned pk2(float a, float b) {
  return (unsigned)f2bf(a) | ((unsigned)f2bf(b) << 16);
}
__device__ __forceinline__ int swzc(int chunk, int row) {
  return (chunk & ~7) | ((chunk ^ row) & 7);
}

__device__ __forceinline__ f32x4 mfma_bf16(uint4 a, uint4 b, f32x4 c) {
  return __builtin_amdgcn_mfma_f32_16x16x32_bf16(
      __builtin_bit_cast(bf16x8, a), __builtin_bit_cast(bf16x8, b), c, 0, 0, 0);
}

// ---------------------------------------------------------------------------
// prep_edge: build the edge-MLP weight image (transposed bf16, chunk-swizzled,
// exact former-LDS byte layout) into d_out. 120 blocks x 256 thr.
// regions (byte offsets): em1 0 | em2 8192 | em3 16384 | at1e 20480 |
//                         at2 28672 | eg1e 32768 | eg2 40960 | end 73728
// ---------------------------------------------------------------------------
__global__ __launch_bounds__(256) void k_prep_edge(
    const float* __restrict__ em_w1, const float* __restrict__ em_w2,
    const float* __restrict__ em_w3, const float* __restrict__ at_w1,
    const float* __restrict__ at_w2, const float* __restrict__ eg_w1,
    const float* __restrict__ eg_w2, unsigned char* __restrict__ img)
{
  int idx = blockIdx.x * 256 + threadIdx.x;   // 0..30719
  const float* src; int KV, RO, k, l, ldw;
  if (idx < 2048)       { src = em_w1;          KV = 18; RO = 0;     k = idx>>6;  l = idx&63;  ldw = 64; }
  else if (idx < 6144)  { src = em_w2;          KV = 64; RO = 8192;  int e = idx-2048;  k = e>>6; l = e&63;  ldw = 64; }
  else if (idx < 8192)  { src = em_w3;          KV = 64; RO = 16384; int e = idx-6144;  k = e>>5; l = e&31;  ldw = 32; }
  else if (idx < 10240) { src = at_w1 + 512*64; KV = 32; RO = 20480; int e = idx-8192;  k = e>>6; l = e&63;  ldw = 64; }
  else if (idx < 12288) { src = at_w2;          KV = 64; RO = 28672; int e = idx-10240; k = e>>5; l = e&31;  ldw = 32; }
  else if (idx < 14336) { src = eg_w1 + 256*64; KV = 32; RO = 32768; int e = idx-12288; k = e>>6; l = e&63;  ldw = 64; }
  else                  { src = eg_w2;          KV = 64; RO = 40960; int e = idx-14336; k = e>>8; l = e&255; ldw = 256; }
  float v = (k < KV) ? src[(size_t)k*ldw + l] : 0.f;
  *(unsigned short*)(img + RO + l*128 + ((((k>>3) ^ (l&7))) << 4) + ((k&7) << 1)) = f2bf(v);
}

// ---------------------------------------------------------------------------
// prep_node: gather node-transform weights into Wnode [704 cols][256 k] bf16.
// ---------------------------------------------------------------------------
__global__ __launch_bounds__(256) void k_prep_node(
    const float* __restrict__ st_w, const float* __restrict__ nt_w,
    const float* __restrict__ at_w1, const float* __restrict__ eg_w1,
    float* __restrict__ ws)
{
  unsigned char* dst = (unsigned char*)(ws + OFF_WN);
  int idx = blockIdx.x * 256 + threadIdx.x;       // 704*32 = 22528
  int col = idx >> 5, ch = idx & 31;
  const float* src; int ld, c;
  if (col < 256)      { src = st_w;           ld = 256; c = col; }
  else if (col < 512) { src = nt_w;           ld = 256; c = col - 256; }
  else if (col < 576) { src = at_w1;          ld = 64;  c = col - 512; }
  else if (col < 640) { src = at_w1 + 256*64; ld = 64;  c = col - 576; }
  else                { src = eg_w1;          ld = 64;  c = col - 640; }
  float e[8];
  #pragma unroll
  for (int q = 0; q < 8; ++q) e[q] = src[(size_t)(ch*8+q)*ld + c];
  uint4 v = make_uint4(pk2(e[0],e[1]), pk2(e[2],e[3]), pk2(e[4],e[5]), pk2(e[6],e[7]));
  *(uint4*)(dst + (size_t)col*512 + swzc(ch, col)*16) = v;
}

// ---------------------------------------------------------------------------
// prep_out: cb_w1 -> W1 [256 cols][512 k] bf16; cb_w2 -> W2 [256][256].
// ---------------------------------------------------------------------------
__global__ __launch_bounds__(256) void k_prep_out(
    const float* __restrict__ cb_w1, const float* __restrict__ cb_w2,
    float* __restrict__ ws)
{
  int bid = blockIdx.x;
  if (bid < 64) {
    unsigned char* dst = (unsigned char*)(ws + OFF_W1);
    int idx = bid * 256 + threadIdx.x;
    int col = idx >> 6, ch = idx & 63;
    float e[8];
    #pragma unroll
    for (int q = 0; q < 8; ++q) e[q] = cb_w1[(size_t)(ch*8+q)*256 + col];
    uint4 v = make_uint4(pk2(e[0],e[1]), pk2(e[2],e[3]), pk2(e[4],e[5]), pk2(e[6],e[7]));
    *(uint4*)(dst + (size_t)col*1024 + swzc(ch, col)*16) = v;
  } else {
    unsigned char* dst = (unsigned char*)(ws + OFF_W2);
    int idx = (bid - 64) * 256 + threadIdx.x;
    int col = idx >> 5, ch = idx & 31;
    float e[8];
    #pragma unroll
    for (int q = 0; q < 8; ++q) e[q] = cb_w2[(size_t)(ch*8+q)*256 + col];
    uint4 v = make_uint4(pk2(e[0],e[1]), pk2(e[2],e[3]), pk2(e[4],e[5]), pk2(e[6],e[7]));
    *(uint4*)(dst + (size_t)col*512 + swzc(ch, col)*16) = v;
  }
}

// ---------------------------------------------------------------------------
// k_node (MFMA): C[1024 x 704] = x[1024 x 256] @ Wnode.
// SF row-major+bias; NBR^T/AJ^T/EGX^T stored [b][col][row] via float4 stores.
// ---------------------------------------------------------------------------
__global__ __launch_bounds__(256) void k_node(
    const float* __restrict__ x,
    const float* __restrict__ st_b, const float* __restrict__ nt_b,
    float* __restrict__ ws)
{
  __shared__ __align__(16) unsigned char sA[64*512];   // 32 KB
  const int t = threadIdx.x;
  const int c0 = blockIdx.x * 64, g0 = blockIdx.y * 64;

  for (int idx = t; idx < 64*64; idx += 256) {
    int row = idx >> 6, kq = idx & 63;
    float4 v = *(const float4*)(x + (size_t)(g0 + row)*CC + kq*4);
    uint2 p; p.x = pk2(v.x, v.y); p.y = pk2(v.z, v.w);
    *(uint2*)(sA + row*512 + swzc(kq >> 1, row)*16 + (kq & 1)*8) = p;
  }
  __syncthreads();

  const int wid = t >> 6, lane = t & 63, l4 = lane >> 4, l16 = lane & 15;
  const unsigned char* WN = (const unsigned char*)(ws + OFF_WN);

  uint4 af[8];
  {
    int row = wid*16 + l16;
    #pragma unroll
    for (int f = 0; f < 8; ++f)
      af[f] = *(const uint4*)(sA + row*512 + swzc(l4 + 4*f, row)*16);
  }

  #pragma unroll
  for (int ct = 0; ct < 4; ++ct) {
    int gcol = c0 + ct*16 + l16;
    f32x4 acc = {0.f, 0.f, 0.f, 0.f};
    #pragma unroll
    for (int f = 0; f < 8; ++f) {
      uint4 bfr = *(const uint4*)(WN + (size_t)gcol*512 + swzc(l4 + 4*f, gcol)*16);
      acc = mfma_bf16(af[f], bfr, acc);
    }
    int gr0 = g0 + wid*16 + l4*4;
    int bb = gr0 >> 9, n0 = gr0 & 511;
    if (gcol < 256) {
      float bz = st_b[gcol];
      #pragma unroll
      for (int r = 0; r < 4; ++r) ws[OFF_SF + (size_t)(gr0+r)*OO + gcol] = acc[r] + bz;
    } else if (gcol < 512) {
      int c = gcol - 256;
      float bz = nt_b[c];
      f32x4 v = {acc[0]+bz, acc[1]+bz, acc[2]+bz, acc[3]+bz};
      *(f32x4*)(ws + OFF_NBR + ((size_t)bb*256 + c)*512 + n0) = v;
    } else if (gcol < 576) {
      #pragma unroll
      for (int r = 0; r < 4; ++r) ws[OFF_AI + (size_t)(gr0+r)*64 + (gcol-512)] = acc[r];
    } else if (gcol < 640) {
      int c = gcol - 576;
      *(f32x4*)(ws + OFF_AJ + ((size_t)bb*64 + c)*512 + n0) = acc;
    } else {
      int c = gcol - 640;
      *(f32x4*)(ws + OFF_EGX + ((size_t)bb*64 + c)*512 + n0) = acc;
    }
  }
}

// ---------------------------------------------------------------------------
// k_edge: fused per-row edge kernel, full-MFMA. 1 block per (i,b). 512 thr.
// Weights read directly from the L2-hot pre-swizzled global image.
// LDS ~80 KB -> 2 blocks/CU (4 waves/SIMD).
// ---------------------------------------------------------------------------
__global__ __launch_bounds__(512, 4) void k_edge(
    const int*   __restrict__ adj,
    const float* __restrict__ ef_g,
    const unsigned char* __restrict__ wimg,
    const float* __restrict__ em_b1g, const float* __restrict__ em_b2g,
    const float* __restrict__ em_b3g,
    const float* __restrict__ at_b1g, const float* __restrict__ at_b2g,
    const float* __restrict__ at_w3g, const float* __restrict__ at_b3g,
    const float* __restrict__ eg_b1g, const float* __restrict__ eg_b2g,
    float* __restrict__ ws)
{
  __shared__ __align__(16) unsigned char s_act[512*128];   // 64 KB activation bounce
  __shared__ float s_bem1[64], s_bem2[64], s_bem3[32];
  __shared__ float s_t1init[64], s_bat2[32], s_w3[32];
  __shared__ float s_beg1[64], s_beg2[256];
  __shared__ float s_sc[512], s_maskf[512], s_red[8];
  __shared__ float s_msg[8][256];

  const int t = threadIdx.x;
  const int i = blockIdx.x, b = blockIdx.y;
  const int wid = t >> 6, lane = t & 63, l4 = lane >> 4, l16 = lane & 15;
  const int R = wid * 64;

  const unsigned char* Wem1 = wimg;
  const unsigned char* Wem2 = wimg + 8192;
  const unsigned char* Wem3 = wimg + 16384;
  const unsigned char* Wat1 = wimg + 20480;
  const unsigned char* Wat2 = wimg + 28672;
  const unsigned char* Weg1 = wimg + 32768;
  const unsigned char* Weg2 = wimg + 40960;

  if (t < 64) {
    s_bem1[t]   = em_b1g[t];
    s_bem2[t]   = em_b2g[t];
    s_t1init[t] = ws[OFF_AI + (size_t)(b*NN + i)*64 + t] + at_b1g[t];
    s_beg1[t]   = eg_b1g[t];
  } else if (t < 96)  { s_bem3[t-64]  = em_b3g[t-64]; }
  else if (t < 128)   { s_bat2[t-96]  = at_b2g[t-96]; }
  else if (t < 160)   { s_w3[t-128]   = at_w3g[t-128]; }
  if (t < 256) s_beg2[t] = eg_b2g[t];
  const float atb3 = at_b3g[0];

  s_maskf[t] = adj[(size_t)(b*NN + i)*NN + t] > 0 ? 1.f : 0.f;

  // stage ef row (pad 18 -> 32, bf16, swizzled)
  {
    const int j = t;
    const float* efp = ef_g + ((size_t)(b*NN + i)*NN + j) * EE;
    float e[32];
    #pragma unroll
    for (int k = 0; k < 9; ++k) { float2 v2 = *(const float2*)(efp + 2*k); e[2*k] = v2.x; e[2*k+1] = v2.y; }
    #pragma unroll
    for (int k = EE; k < 32; ++k) e[k] = 0.f;
    #pragma unroll
    for (int c = 0; c < 4; ++c) {
      uint4 u = make_uint4(pk2(e[c*8+0],e[c*8+1]), pk2(e[c*8+2],e[c*8+3]),
                           pk2(e[c*8+4],e[c*8+5]), pk2(e[c*8+6],e[c*8+7]));
      *(uint4*)(s_act + j*128 + ((c ^ (j & 7)) << 4)) = u;
    }
  }
  __syncthreads();

  auto loadA = [&](int rb, int f) -> uint4 {
    int rw = rb + l16;
    return *(const uint4*)(s_act + rw*128 + (((l4 + 4*f) ^ (rw & 7)) << 4));
  };
  auto loadB = [&](const unsigned char* w, int ct, int f) -> uint4 {
    int rw = ct*16 + l16;
    return *(const uint4*)(w + rw*128 + (((l4 + 4*f) ^ (rw & 7)) << 4));
  };
  auto storeCR = [&](int rb, int ct, const f32x4& c) {
    int col = ct*16 + l16;
    #pragma unroll
    for (int r = 0; r < 4; ++r) {
      int rw = rb + l4*4 + r;
      *(unsigned short*)(s_act + rw*128 + (((col >> 3) ^ (rw & 7)) << 4) + ((col & 7) << 1))
          = f2bf(fmaxf(c[r], 0.f));
    }
  };

  const float* ajT  = ws + OFF_AJ  + (size_t)b*64*512;    // [col][row]
  const float* egT  = ws + OFF_EGX + (size_t)b*64*512;    // [col][row]
  const float* nbrT = ws + OFF_NBR + (size_t)b*256*512;   // [col][row]

  uint4 peA[4];

  // ---- L1: ef(K32) -> h1(64) ----
  {
    uint4 B[4];
    #pragma unroll
    for (int ct = 0; ct < 4; ++ct) B[ct] = loadB(Wem1, ct, 0);
    #pragma unroll
    for (int st = 0; st < 4; ++st) {
      int rb = R + st*16;
      uint4 a = loadA(rb, 0);
      #pragma unroll
      for (int ct = 0; ct < 4; ++ct) {
        float bz = s_bem1[ct*16 + l16];
        f32x4 c = {bz, bz, bz, bz};
        c = mfma_bf16(a, B[ct], c);
        storeCR(rb, ct, c);
      }
    }
  }
  // ---- L2: h1(K64) -> h2(64) ----
  {
    uint4 B[4][2];
    #pragma unroll
    for (int ct = 0; ct < 4; ++ct) { B[ct][0] = loadB(Wem2, ct, 0); B[ct][1] = loadB(Wem2, ct, 1); }
    #pragma unroll
    for (int st = 0; st < 4; ++st) {
      int rb = R + st*16;
      uint4 a0 = loadA(rb, 0), a1 = loadA(rb, 1);
      #pragma unroll
      for (int ct = 0; ct < 4; ++ct) {
        float bz = s_bem2[ct*16 + l16];
        f32x4 c = {bz, bz, bz, bz};
        c = mfma_bf16(a0, B[ct][0], c);
        c = mfma_bf16(a1, B[ct][1], c);
        storeCR(rb, ct, c);
      }
    }
  }
  // ---- L3: h2(K64) -> pe(32); keep pe A-frags in registers ----
  {
    uint4 B[2][2];
    #pragma unroll
    for (int ct = 0; ct < 2; ++ct) { B[ct][0] = loadB(Wem3, ct, 0); B[ct][1] = loadB(Wem3, ct, 1); }
    #pragma unroll
    for (int st = 0; st < 4; ++st) {
      int rb = R + st*16;
      uint4 a0 = loadA(rb, 0), a1 = loadA(rb, 1);
      #pragma unroll
      for (int ct = 0; ct < 2; ++ct) {
        float bz = s_bem3[ct*16 + l16];
        f32x4 c = {bz, bz, bz, bz};
        c = mfma_bf16(a0, B[ct][0], c);
        c = mfma_bf16(a1, B[ct][1], c);
        storeCR(rb, ct, c);
      }
      peA[st] = loadA(rb, 0);
    }
  }
  // ---- L4a: t1 = relu(a_i + a_j + b1 + pe @ at_w1e) ----
  {
    uint4 B[4];
    #pragma unroll
    for (int ct = 0; ct < 4; ++ct) B[ct] = loadB(Wat1, ct, 0);
    #pragma unroll
    for (int st = 0; st < 4; ++st) {
      int rb = R + st*16;
      #pragma unroll
      for (int ct = 0; ct < 4; ++ct) {
        int col = ct*16 + l16;
        f32x4 av = *(const f32x4*)(ajT + (size_t)col*512 + rb + l4*4);
        float ti = s_t1init[col];
        f32x4 c = {ti + av[0], ti + av[1], ti + av[2], ti + av[3]};
        c = mfma_bf16(peA[st], B[ct], c);
        storeCR(rb, ct, c);
      }
    }
  }
  // ---- L5: t2 = relu(t1 @ at_w2 + b2); score = t2 . w3 + b3 ----
  {
    uint4 B[2][2];
    #pragma unroll
    for (int ct = 0; ct < 2; ++ct) { B[ct][0] = loadB(Wat2, ct, 0); B[ct][1] = loadB(Wat2, ct, 1); }
    #pragma unroll
    for (int st = 0; st < 4; ++st) {
      int rb = R + st*16;
      uint4 a0 = loadA(rb, 0), a1 = loadA(rb, 1);
      float b0 = s_bat2[l16], b1v = s_bat2[16 + l16];
      f32x4 c0 = {b0, b0, b0, b0}, c1 = {b1v, b1v, b1v, b1v};
      c0 = mfma_bf16(a0, B[0][0], c0); c0 = mfma_bf16(a1, B[0][1], c0);
      c1 = mfma_bf16(a0, B[1][0], c1); c1 = mfma_bf16(a1, B[1][1], c1);
      float w3a = s_w3[l16], w3b = s_w3[16 + l16];
      #pragma unroll
      for (int r = 0; r < 4; ++r) {
        float val = fmaxf(c0[r], 0.f)*w3a + fmaxf(c1[r], 0.f)*w3b;
        val += __shfl_xor(val, 1); val += __shfl_xor(val, 2);
        val += __shfl_xor(val, 4); val += __shfl_xor(val, 8);
        if (l16 == 0) s_sc[rb + l4*4 + r] = val + atb3;
      }
    }
  }
  // ---- L4b: g1 = relu(eg_x_j + eg_b1 + pe @ eg_w1e) -> s_act ----
  {
    uint4 B[4];
    #pragma unroll
    for (int ct = 0; ct < 4; ++ct) B[ct] = loadB(Weg1, ct, 0);
    #pragma unroll
    for (int st = 0; st < 4; ++st) {
      int rb = R + st*16;
      #pragma unroll
      for (int ct = 0; ct < 4; ++ct) {
        int col = ct*16 + l16;
        f32x4 ev = *(const f32x4*)(egT + (size_t)col*512 + rb + l4*4);
        float bg = s_beg1[col];
        f32x4 c = {bg + ev[0], bg + ev[1], bg + ev[2], bg + ev[3]};
        c = mfma_bf16(peA[st], B[ct], c);
        storeCR(rb, ct, c);
      }
    }
  }
  __syncthreads();

  // ---------------- masked softmax over j ----------------
  {
    float mf = s_maskf[t];
    float v  = mf > 0.f ? s_sc[t] : -1e9f;
    float m = v;
    #pragma unroll
    for (int d = 1; d < 64; d <<= 1) m = fmaxf(m, __shfl_xor(m, d));
    if (lane == 0) s_red[wid] = m;
    __syncthreads();
    float mx = s_red[0];
    #pragma unroll
    for (int w = 1; w < 8; ++w) mx = fmaxf(mx, s_red[w]);
    float p = mf > 0.f ? __expf(v - mx) : 0.f;
    float sm = p;
    #pragma unroll
    for (int d = 1; d < 64; d <<= 1) sm += __shfl_xor(sm, d);
    __syncthreads();
    if (lane == 0) s_red[wid] = sm;
    __syncthreads();
    float den = 0.f;
    #pragma unroll
    for (int w = 0; w < 8; ++w) den += s_red[w];
    float inv = den > 0.f ? 1.f/den : 0.f;
    s_sc[t] = p * inv;
  }
  __syncthreads();

  // ---- L7: z = g1 @ eg_w2 + b2; msg += rcp(1+exp(-z)) * attn * nbr ----
  {
    uint4 gA[4][2];
    #pragma unroll
    for (int st = 0; st < 4; ++st) { gA[st][0] = loadA(R + st*16, 0); gA[st][1] = loadA(R + st*16, 1); }
    float attnR[16];
    #pragma unroll
    for (int q = 0; q < 16; ++q) attnR[q] = s_sc[R + (q>>2)*16 + l4*4 + (q&3)];

    for (int ct = 0; ct < 16; ++ct) {
      uint4 B0 = loadB(Weg2, ct, 0), B1 = loadB(Weg2, ct, 1);
      int col = ct*16 + l16;
      float bz = s_beg2[col];
      const float* nbrc = nbrT + (size_t)col*512 + R + l4*4;
      float msgp = 0.f;
      #pragma unroll
      for (int st = 0; st < 4; ++st) {
        f32x4 nv = *(const f32x4*)(nbrc + st*16);
        f32x4 c = {bz, bz, bz, bz};
        c = mfma_bf16(gA[st][0], B0, c);
        c = mfma_bf16(gA[st][1], B1, c);
        #pragma unroll
        for (int r = 0; r < 4; ++r) {
          float g = __builtin_amdgcn_rcpf(1.f + __expf(-c[r]));
          msgp += g * attnR[st*4 + r] * nv[r];
        }
      }
      msgp += __shfl_xor(msgp, 16);
      msgp += __shfl_xor(msgp, 32);
      if (lane < 16) s_msg[wid][ct*16 + lane] = msgp;
    }
  }
  __syncthreads();
  if (t < 256) {
    float s = 0.f;
    #pragma unroll
    for (int w = 0; w < 8; ++w) s += s_msg[w][t];
    ws[OFF_MSG + (size_t)(b*NN + i)*OO + t] = s;
  }
}

// ---------------------------------------------------------------------------
// k_out (MFMA): unchanged from round 3.
// ---------------------------------------------------------------------------
__global__ __launch_bounds__(256) void k_out(
    const float* __restrict__ cb_b1, const float* __restrict__ cb_b2,
    const float* __restrict__ ws, float* __restrict__ out)
{
  __shared__ __align__(16) unsigned char sA[16*1024];
  __shared__ __align__(16) unsigned char sT[16*512];
  const int t = threadIdx.x;
  const int g0 = blockIdx.x * 16;

  for (int idx = t; idx < 16*128; idx += 256) {
    int row = idx >> 7, kq = idx & 127;
    const float* src = (kq < 64)
        ? ws + OFF_SF  + (size_t)(g0 + row)*OO + kq*4
        : ws + OFF_MSG + (size_t)(g0 + row)*OO + (kq - 64)*4;
    float4 v = *(const float4*)src;
    uint2 p; p.x = pk2(v.x, v.y); p.y = pk2(v.z, v.w);
    *(uint2*)(sA + row*1024 + swzc(kq >> 1, row)*16 + (kq & 1)*8) = p;
  }
  __syncthreads();

  const int wid = t >> 6, lane = t & 63, l4 = lane >> 4, l16 = lane & 15;
  const unsigned char* W1 = (const unsigned char*)(ws + OFF_W1);
  const unsigned char* W2 = (const unsigned char*)(ws + OFF_W2);

  {
    uint4 af[16];
    #pragma unroll
    for (int f = 0; f < 16; ++f)
      af[f] = *(const uint4*)(sA + l16*1024 + swzc(l4 + 4*f, l16)*16);
    #pragma unroll
    for (int c = 0; c < 4; ++c) {
      int col = wid*64 + c*16 + l16;
      float bz = cb_b1[col];
      f32x4 acc = {bz, bz, bz, bz};
      #pragma unroll
      for (int f = 0; f < 16; ++f) {
        uint4 bfr = *(const uint4*)(W1 + (size_t)col*1024 + swzc(l4 + 4*f, col)*16);
        acc = mfma_bf16(af[f], bfr, acc);
      }
      #pragma unroll
      for (int r = 0; r < 4; ++r) {
        int row = l4*4 + r;
        *(unsigned short*)(sT + row*512 + swzc(col >> 3, row)*16 + (col & 7)*2)
            = f2bf(fmaxf(acc[r], 0.f));
      }
    }
  }
  __syncthreads();

  {
    uint4 tf[8];
    #pragma unroll
    for (int f = 0; f < 8; ++f)
      tf[f] = *(const uint4*)(sT + l16*512 + swzc(l4 + 4*f, l16)*16);
    #pragma unroll
    for (int c = 0; c < 4; ++c) {
      int col = wid*64 + c*16 + l16;
      float bz = cb_b2[col];
      f32x4 acc = {bz, bz, bz, bz};
      #pragma unroll
      for (int f = 0; f < 8; ++f) {
        uint4 bfr = *(const uint4*)(W2 + (size_t)col*512 + swzc(l4 + 4*f, col)*16);
        acc = mfma_bf16(tf[f], bfr, acc);
      }
      #pragma unroll
      for (int r = 0; r < 4; ++r)
        out[(size_t)(g0 + l4*4 + r)*OO + col] = acc[r];
    }
  }
}

extern "C" void kernel_launch(void* const* d_in, const int* in_sizes, int n_in,
                              void* d_out, int out_size, void* d_ws, size_t ws_size,
                              hipStream_t stream) {
  const float* x     = (const float*)d_in[0];
  const int*   adj   = (const int*)  d_in[1];
  const float* ef    = (const float*)d_in[2];
  const float* st_w  = (const float*)d_in[3];
  const float* st_b  = (const float*)d_in[4];
  const float* nt_w  = (const float*)d_in[5];
  const float* nt_b  = (const float*)d_in[6];
  const float* em_w1 = (const float*)d_in[7];
  const float* em_b1 = (const float*)d_in[8];
  const float* em_w2 = (const float*)d_in[9];
  const float* em_b2 = (const float*)d_in[10];
  const float* em_w3 = (const float*)d_in[11];
  const float* em_b3 = (const float*)d_in[12];
  const float* at_w1 = (const float*)d_in[13];
  const float* at_b1 = (const float*)d_in[14];
  const float* at_w2 = (const float*)d_in[15];
  const float* at_b2 = (const float*)d_in[16];
  const float* at_w3 = (const float*)d_in[17];
  const float* at_b3 = (const float*)d_in[18];
  const float* eg_w1 = (const float*)d_in[19];
  const float* eg_b1 = (const float*)d_in[20];
  const float* eg_w2 = (const float*)d_in[21];
  const float* eg_b2 = (const float*)d_in[22];
  const float* cb_w1 = (const float*)d_in[23];
  const float* cb_b1 = (const float*)d_in[24];
  const float* cb_w2 = (const float*)d_in[25];
  const float* cb_b2 = (const float*)d_in[26];
  float* ws  = (float*)d_ws;
  float* out = (float*)d_out;
  unsigned char* wimg = (unsigned char*)d_out;   // dead until k_out overwrites

  k_prep_edge<<<dim3(120), dim3(256), 0, stream>>>(em_w1, em_w2, em_w3, at_w1, at_w2, eg_w1, eg_w2, wimg);
  k_prep_node<<<dim3(88), dim3(256), 0, stream>>>(st_w, nt_w, at_w1, eg_w1, ws);
  k_node<<<dim3(11, 16), dim3(256), 0, stream>>>(x, st_b, nt_b, ws);
  k_edge<<<dim3(NN, BB), dim3(512), 0, stream>>>(adj, ef, wimg,
      em_b1, em_b2, em_b3, at_b1, at_b2, at_w3, at_b3, eg_b1, eg_b2, ws);
  k_prep_out<<<dim3(96), dim3(256), 0, stream>>>(cb_w1, cb_w2, ws);
  k_out<<<dim3(64), dim3(256), 0, stream>>>(cb_b1, cb_b2, ws, out);
}

// Round 5
// 174.995 us; speedup vs baseline: 4.7939x; 1.0596x over previous
//
#include <hip/hip_runtime.h>

#define BB 2
#define NN 512
#define CC 256
#define OO 256
#define EE 18

// workspace layout (float offsets)
#define OFF_SF   0
#define OFF_NBR  (BB*NN*OO)
#define OFF_AI   (OFF_NBR + BB*NN*OO)
#define OFF_AJ   (OFF_AI + BB*NN*64)
#define OFF_EGX  (OFF_AJ + BB*NN*64)
#define OFF_MSG  (OFF_EGX + BB*NN*64)
// NOTE: NBR/AJ/EGX are stored TRANSPOSED: [b][col][row]
// aliased weight-staging regions (lifetime-disjoint):
// WN in MSG region (prep_node -> k_node, clobbered later by k_edge MSG writes).
// W1/W2 in AI/AJ regions (prep_out runs AFTER k_edge).
// Edge-weight image lives in d_out (dead until k_out overwrites it).
#define OFF_WN   OFF_MSG
#define OFF_W1   OFF_AI
#define OFF_W2   OFF_AJ

typedef float f32x4 __attribute__((ext_vector_type(4)));
typedef __bf16 bf16x8 __attribute__((ext_vector_type(8)));

__device__ __forceinline__ unsigned short f2bf(float f) {
  unsigned u = __float_as_uint(f);
  u += 0x7fffu + ((u >> 16) & 1u);          // RNE
  return (unsigned short)(u >> 16);
}
__device__ __forceinline__ unsigned pk2(float a, float b) {
  return (unsigned)f2bf(a) | ((unsigned)f2bf(b) << 16);
}
__device__ __forceinline__ int swzc(int chunk, int row) {
  return (chunk & ~7) | ((chunk ^ row) & 7);
}

__device__ __forceinline__ f32x4 mfma_bf16(uint4 a, uint4 b, f32x4 c) {
  return __builtin_amdgcn_mfma_f32_16x16x32_bf16(
      __builtin_bit_cast(bf16x8, a), __builtin_bit_cast(bf16x8, b), c, 0, 0, 0);
}

// ---------------------------------------------------------------------------
// prep_edge: build the edge-MLP weight image (transposed bf16, chunk-swizzled,
// exact former-LDS byte layout) into d_out. 120 blocks x 256 thr.
// regions (byte offsets): em1 0 | em2 8192 | em3 16384 | at1e 20480 |
//                         at2 28672 | eg1e 32768 | eg2 40960 | end 73728
// ---------------------------------------------------------------------------
__global__ __launch_bounds__(256) void k_prep_edge(
    const float* __restrict__ em_w1, const float* __restrict__ em_w2,
    const float* __restrict__ em_w3, const float* __restrict__ at_w1,
    const float* __restrict__ at_w2, const float* __restrict__ eg_w1,
    const float* __restrict__ eg_w2, unsigned char* __restrict__ img)
{
  int idx = blockIdx.x * 256 + threadIdx.x;   // 0..30719
  const float* src; int KV, RO, k, l, ldw;
  if (idx < 2048)       { src = em_w1;          KV = 18; RO = 0;     k = idx>>6;  l = idx&63;  ldw = 64; }
  else if (idx < 6144)  { src = em_w2;          KV = 64; RO = 8192;  int e = idx-2048;  k = e>>6; l = e&63;  ldw = 64; }
  else if (idx < 8192)  { src = em_w3;          KV = 64; RO = 16384; int e = idx-6144;  k = e>>5; l = e&31;  ldw = 32; }
  else if (idx < 10240) { src = at_w1 + 512*64; KV = 32; RO = 20480; int e = idx-8192;  k = e>>6; l = e&63;  ldw = 64; }
  else if (idx < 12288) { src = at_w2;          KV = 64; RO = 28672; int e = idx-10240; k = e>>5; l = e&31;  ldw = 32; }
  else if (idx < 14336) { src = eg_w1 + 256*64; KV = 32; RO = 32768; int e = idx-12288; k = e>>6; l = e&63;  ldw = 64; }
  else                  { src = eg_w2;          KV = 64; RO = 40960; int e = idx-14336; k = e>>8; l = e&255; ldw = 256; }
  float v = (k < KV) ? src[(size_t)k*ldw + l] : 0.f;
  *(unsigned short*)(img + RO + l*128 + ((((k>>3) ^ (l&7))) << 4) + ((k&7) << 1)) = f2bf(v);
}

// ---------------------------------------------------------------------------
// prep_node: gather node-transform weights into Wnode [704 cols][256 k] bf16.
// ---------------------------------------------------------------------------
__global__ __launch_bounds__(256) void k_prep_node(
    const float* __restrict__ st_w, const float* __restrict__ nt_w,
    const float* __restrict__ at_w1, const float* __restrict__ eg_w1,
    float* __restrict__ ws)
{
  unsigned char* dst = (unsigned char*)(ws + OFF_WN);
  int idx = blockIdx.x * 256 + threadIdx.x;       // 704*32 = 22528
  int col = idx >> 5, ch = idx & 31;
  const float* src; int ld, c;
  if (col < 256)      { src = st_w;           ld = 256; c = col; }
  else if (col < 512) { src = nt_w;           ld = 256; c = col - 256; }
  else if (col < 576) { src = at_w1;          ld = 64;  c = col - 512; }
  else if (col < 640) { src = at_w1 + 256*64; ld = 64;  c = col - 576; }
  else                { src = eg_w1;          ld = 64;  c = col - 640; }
  float e[8];
  #pragma unroll
  for (int q = 0; q < 8; ++q) e[q] = src[(size_t)(ch*8+q)*ld + c];
  uint4 v = make_uint4(pk2(e[0],e[1]), pk2(e[2],e[3]), pk2(e[4],e[5]), pk2(e[6],e[7]));
  *(uint4*)(dst + (size_t)col*512 + swzc(ch, col)*16) = v;
}

// ---------------------------------------------------------------------------
// prep_out: cb_w1 -> W1 [256 cols][512 k] bf16; cb_w2 -> W2 [256][256].
// ---------------------------------------------------------------------------
__global__ __launch_bounds__(256) void k_prep_out(
    const float* __restrict__ cb_w1, const float* __restrict__ cb_w2,
    float* __restrict__ ws)
{
  int bid = blockIdx.x;
  if (bid < 64) {
    unsigned char* dst = (unsigned char*)(ws + OFF_W1);
    int idx = bid * 256 + threadIdx.x;
    int col = idx >> 6, ch = idx & 63;
    float e[8];
    #pragma unroll
    for (int q = 0; q < 8; ++q) e[q] = cb_w1[(size_t)(ch*8+q)*256 + col];
    uint4 v = make_uint4(pk2(e[0],e[1]), pk2(e[2],e[3]), pk2(e[4],e[5]), pk2(e[6],e[7]));
    *(uint4*)(dst + (size_t)col*1024 + swzc(ch, col)*16) = v;
  } else {
    unsigned char* dst = (unsigned char*)(ws + OFF_W2);
    int idx = (bid - 64) * 256 + threadIdx.x;
    int col = idx >> 5, ch = idx & 31;
    float e[8];
    #pragma unroll
    for (int q = 0; q < 8; ++q) e[q] = cb_w2[(size_t)(ch*8+q)*256 + col];
    uint4 v = make_uint4(pk2(e[0],e[1]), pk2(e[2],e[3]), pk2(e[4],e[5]), pk2(e[6],e[7]));
    *(uint4*)(dst + (size_t)col*512 + swzc(ch, col)*16) = v;
  }
}

// ---------------------------------------------------------------------------
// k_node (MFMA): C[1024 x 704] = x[1024 x 256] @ Wnode.
// SF row-major+bias; NBR^T/AJ^T/EGX^T stored [b][col][row] via float4 stores.
// ---------------------------------------------------------------------------
__global__ __launch_bounds__(256) void k_node(
    const float* __restrict__ x,
    const float* __restrict__ st_b, const float* __restrict__ nt_b,
    float* __restrict__ ws)
{
  __shared__ __align__(16) unsigned char sA[64*512];   // 32 KB
  const int t = threadIdx.x;
  const int c0 = blockIdx.x * 64, g0 = blockIdx.y * 64;

  for (int idx = t; idx < 64*64; idx += 256) {
    int row = idx >> 6, kq = idx & 63;
    float4 v = *(const float4*)(x + (size_t)(g0 + row)*CC + kq*4);
    uint2 p; p.x = pk2(v.x, v.y); p.y = pk2(v.z, v.w);
    *(uint2*)(sA + row*512 + swzc(kq >> 1, row)*16 + (kq & 1)*8) = p;
  }
  __syncthreads();

  const int wid = t >> 6, lane = t & 63, l4 = lane >> 4, l16 = lane & 15;
  const unsigned char* WN = (const unsigned char*)(ws + OFF_WN);

  uint4 af[8];
  {
    int row = wid*16 + l16;
    #pragma unroll
    for (int f = 0; f < 8; ++f)
      af[f] = *(const uint4*)(sA + row*512 + swzc(l4 + 4*f, row)*16);
  }

  #pragma unroll
  for (int ct = 0; ct < 4; ++ct) {
    int gcol = c0 + ct*16 + l16;
    f32x4 acc = {0.f, 0.f, 0.f, 0.f};
    #pragma unroll
    for (int f = 0; f < 8; ++f) {
      uint4 bfr = *(const uint4*)(WN + (size_t)gcol*512 + swzc(l4 + 4*f, gcol)*16);
      acc = mfma_bf16(af[f], bfr, acc);
    }
    int gr0 = g0 + wid*16 + l4*4;
    int bb = gr0 >> 9, n0 = gr0 & 511;
    if (gcol < 256) {
      float bz = st_b[gcol];
      #pragma unroll
      for (int r = 0; r < 4; ++r) ws[OFF_SF + (size_t)(gr0+r)*OO + gcol] = acc[r] + bz;
    } else if (gcol < 512) {
      int c = gcol - 256;
      float bz = nt_b[c];
      f32x4 v = {acc[0]+bz, acc[1]+bz, acc[2]+bz, acc[3]+bz};
      *(f32x4*)(ws + OFF_NBR + ((size_t)bb*256 + c)*512 + n0) = v;
    } else if (gcol < 576) {
      #pragma unroll
      for (int r = 0; r < 4; ++r) ws[OFF_AI + (size_t)(gr0+r)*64 + (gcol-512)] = acc[r];
    } else if (gcol < 640) {
      int c = gcol - 576;
      *(f32x4*)(ws + OFF_AJ + ((size_t)bb*64 + c)*512 + n0) = acc;
    } else {
      int c = gcol - 640;
      *(f32x4*)(ws + OFF_EGX + ((size_t)bb*64 + c)*512 + n0) = acc;
    }
  }
}

// ---------------------------------------------------------------------------
// k_edge: fused per-row edge kernel, full-MFMA. 1 block per (i,b). 512 thr.
// Weights read directly from the L2-hot pre-swizzled global image.
// LDS ~80 KB. launch_bounds(512,2): <=256 VGPR -> NO SPILLS (the (512,4)
// variant spilled: WRITE_SIZE 1MB->142MB). Occupancy set by actual VGPR.
// ---------------------------------------------------------------------------
__global__ __launch_bounds__(512, 2) void k_edge(
    const int*   __restrict__ adj,
    const float* __restrict__ ef_g,
    const unsigned char* __restrict__ wimg,
    const float* __restrict__ em_b1g, const float* __restrict__ em_b2g,
    const float* __restrict__ em_b3g,
    const float* __restrict__ at_b1g, const float* __restrict__ at_b2g,
    const float* __restrict__ at_w3g, const float* __restrict__ at_b3g,
    const float* __restrict__ eg_b1g, const float* __restrict__ eg_b2g,
    float* __restrict__ ws)
{
  __shared__ __align__(16) unsigned char s_act[512*128];   // 64 KB activation bounce
  __shared__ float s_bem1[64], s_bem2[64], s_bem3[32];
  __shared__ float s_t1init[64], s_bat2[32], s_w3[32];
  __shared__ float s_beg1[64], s_beg2[256];
  __shared__ float s_sc[512], s_maskf[512], s_red[8];
  __shared__ float s_msg[8][256];

  const int t = threadIdx.x;
  const int i = blockIdx.x, b = blockIdx.y;
  const int wid = t >> 6, lane = t & 63, l4 = lane >> 4, l16 = lane & 15;
  const int R = wid * 64;

  const unsigned char* Wem1 = wimg;
  const unsigned char* Wem2 = wimg + 8192;
  const unsigned char* Wem3 = wimg + 16384;
  const unsigned char* Wat1 = wimg + 20480;
  const unsigned char* Wat2 = wimg + 28672;
  const unsigned char* Weg1 = wimg + 32768;
  const unsigned char* Weg2 = wimg + 40960;

  if (t < 64) {
    s_bem1[t]   = em_b1g[t];
    s_bem2[t]   = em_b2g[t];
    s_t1init[t] = ws[OFF_AI + (size_t)(b*NN + i)*64 + t] + at_b1g[t];
    s_beg1[t]   = eg_b1g[t];
  } else if (t < 96)  { s_bem3[t-64]  = em_b3g[t-64]; }
  else if (t < 128)   { s_bat2[t-96]  = at_b2g[t-96]; }
  else if (t < 160)   { s_w3[t-128]   = at_w3g[t-128]; }
  if (t < 256) s_beg2[t] = eg_b2g[t];
  const float atb3 = at_b3g[0];

  s_maskf[t] = adj[(size_t)(b*NN + i)*NN + t] > 0 ? 1.f : 0.f;

  // stage ef row (pad 18 -> 32, bf16, swizzled)
  {
    const int j = t;
    const float* efp = ef_g + ((size_t)(b*NN + i)*NN + j) * EE;
    float e[32];
    #pragma unroll
    for (int k = 0; k < 9; ++k) { float2 v2 = *(const float2*)(efp + 2*k); e[2*k] = v2.x; e[2*k+1] = v2.y; }
    #pragma unroll
    for (int k = EE; k < 32; ++k) e[k] = 0.f;
    #pragma unroll
    for (int c = 0; c < 4; ++c) {
      uint4 u = make_uint4(pk2(e[c*8+0],e[c*8+1]), pk2(e[c*8+2],e[c*8+3]),
                           pk2(e[c*8+4],e[c*8+5]), pk2(e[c*8+6],e[c*8+7]));
      *(uint4*)(s_act + j*128 + ((c ^ (j & 7)) << 4)) = u;
    }
  }
  __syncthreads();

  auto loadA = [&](int rb, int f) -> uint4 {
    int rw = rb + l16;
    return *(const uint4*)(s_act + rw*128 + (((l4 + 4*f) ^ (rw & 7)) << 4));
  };
  auto loadB = [&](const unsigned char* w, int ct, int f) -> uint4 {
    int rw = ct*16 + l16;
    return *(const uint4*)(w + rw*128 + (((l4 + 4*f) ^ (rw & 7)) << 4));
  };
  auto storeCR = [&](int rb, int ct, const f32x4& c) {
    int col = ct*16 + l16;
    #pragma unroll
    for (int r = 0; r < 4; ++r) {
      int rw = rb + l4*4 + r;
      *(unsigned short*)(s_act + rw*128 + (((col >> 3) ^ (rw & 7)) << 4) + ((col & 7) << 1))
          = f2bf(fmaxf(c[r], 0.f));
    }
  };

  const float* ajT  = ws + OFF_AJ  + (size_t)b*64*512;    // [col][row]
  const float* egT  = ws + OFF_EGX + (size_t)b*64*512;    // [col][row]
  const float* nbrT = ws + OFF_NBR + (size_t)b*256*512;   // [col][row]

  uint4 peA[4];

  // ---- L1: ef(K32) -> h1(64) ----
  {
    uint4 B[4];
    #pragma unroll
    for (int ct = 0; ct < 4; ++ct) B[ct] = loadB(Wem1, ct, 0);
    #pragma unroll
    for (int st = 0; st < 4; ++st) {
      int rb = R + st*16;
      uint4 a = loadA(rb, 0);
      #pragma unroll
      for (int ct = 0; ct < 4; ++ct) {
        float bz = s_bem1[ct*16 + l16];
        f32x4 c = {bz, bz, bz, bz};
        c = mfma_bf16(a, B[ct], c);
        storeCR(rb, ct, c);
      }
    }
  }
  // ---- L2: h1(K64) -> h2(64) ----
  {
    uint4 B[4][2];
    #pragma unroll
    for (int ct = 0; ct < 4; ++ct) { B[ct][0] = loadB(Wem2, ct, 0); B[ct][1] = loadB(Wem2, ct, 1); }
    #pragma unroll
    for (int st = 0; st < 4; ++st) {
      int rb = R + st*16;
      uint4 a0 = loadA(rb, 0), a1 = loadA(rb, 1);
      #pragma unroll
      for (int ct = 0; ct < 4; ++ct) {
        float bz = s_bem2[ct*16 + l16];
        f32x4 c = {bz, bz, bz, bz};
        c = mfma_bf16(a0, B[ct][0], c);
        c = mfma_bf16(a1, B[ct][1], c);
        storeCR(rb, ct, c);
      }
    }
  }
  // ---- L3: h2(K64) -> pe(32); keep pe A-frags in registers ----
  {
    uint4 B[2][2];
    #pragma unroll
    for (int ct = 0; ct < 2; ++ct) { B[ct][0] = loadB(Wem3, ct, 0); B[ct][1] = loadB(Wem3, ct, 1); }
    #pragma unroll
    for (int st = 0; st < 4; ++st) {
      int rb = R + st*16;
      uint4 a0 = loadA(rb, 0), a1 = loadA(rb, 1);
      #pragma unroll
      for (int ct = 0; ct < 2; ++ct) {
        float bz = s_bem3[ct*16 + l16];
        f32x4 c = {bz, bz, bz, bz};
        c = mfma_bf16(a0, B[ct][0], c);
        c = mfma_bf16(a1, B[ct][1], c);
        storeCR(rb, ct, c);
      }
      peA[st] = loadA(rb, 0);
    }
  }
  // ---- L4a: t1 = relu(a_i + a_j + b1 + pe @ at_w1e) ----
  {
    uint4 B[4];
    #pragma unroll
    for (int ct = 0; ct < 4; ++ct) B[ct] = loadB(Wat1, ct, 0);
    #pragma unroll
    for (int st = 0; st < 4; ++st) {
      int rb = R + st*16;
      #pragma unroll
      for (int ct = 0; ct < 4; ++ct) {
        int col = ct*16 + l16;
        f32x4 av = *(const f32x4*)(ajT + (size_t)col*512 + rb + l4*4);
        float ti = s_t1init[col];
        f32x4 c = {ti + av[0], ti + av[1], ti + av[2], ti + av[3]};
        c = mfma_bf16(peA[st], B[ct], c);
        storeCR(rb, ct, c);
      }
    }
  }
  // ---- L5: t2 = relu(t1 @ at_w2 + b2); score = t2 . w3 + b3 ----
  {
    uint4 B[2][2];
    #pragma unroll
    for (int ct = 0; ct < 2; ++ct) { B[ct][0] = loadB(Wat2, ct, 0); B[ct][1] = loadB(Wat2, ct, 1); }
    #pragma unroll
    for (int st = 0; st < 4; ++st) {
      int rb = R + st*16;
      uint4 a0 = loadA(rb, 0), a1 = loadA(rb, 1);
      float b0 = s_bat2[l16], b1v = s_bat2[16 + l16];
      f32x4 c0 = {b0, b0, b0, b0}, c1 = {b1v, b1v, b1v, b1v};
      c0 = mfma_bf16(a0, B[0][0], c0); c0 = mfma_bf16(a1, B[0][1], c0);
      c1 = mfma_bf16(a0, B[1][0], c1); c1 = mfma_bf16(a1, B[1][1], c1);
      float w3a = s_w3[l16], w3b = s_w3[16 + l16];
      #pragma unroll
      for (int r = 0; r < 4; ++r) {
        float val = fmaxf(c0[r], 0.f)*w3a + fmaxf(c1[r], 0.f)*w3b;
        val += __shfl_xor(val, 1); val += __shfl_xor(val, 2);
        val += __shfl_xor(val, 4); val += __shfl_xor(val, 8);
        if (l16 == 0) s_sc[rb + l4*4 + r] = val + atb3;
      }
    }
  }
  // ---- L4b: g1 = relu(eg_x_j + eg_b1 + pe @ eg_w1e) -> s_act ----
  {
    uint4 B[4];
    #pragma unroll
    for (int ct = 0; ct < 4; ++ct) B[ct] = loadB(Weg1, ct, 0);
    #pragma unroll
    for (int st = 0; st < 4; ++st) {
      int rb = R + st*16;
      #pragma unroll
      for (int ct = 0; ct < 4; ++ct) {
        int col = ct*16 + l16;
        f32x4 ev = *(const f32x4*)(egT + (size_t)col*512 + rb + l4*4);
        float bg = s_beg1[col];
        f32x4 c = {bg + ev[0], bg + ev[1], bg + ev[2], bg + ev[3]};
        c = mfma_bf16(peA[st], B[ct], c);
        storeCR(rb, ct, c);
      }
    }
  }
  __syncthreads();

  // ---------------- masked softmax over j ----------------
  {
    float mf = s_maskf[t];
    float v  = mf > 0.f ? s_sc[t] : -1e9f;
    float m = v;
    #pragma unroll
    for (int d = 1; d < 64; d <<= 1) m = fmaxf(m, __shfl_xor(m, d));
    if (lane == 0) s_red[wid] = m;
    __syncthreads();
    float mx = s_red[0];
    #pragma unroll
    for (int w = 1; w < 8; ++w) mx = fmaxf(mx, s_red[w]);
    float p = mf > 0.f ? __expf(v - mx) : 0.f;
    float sm = p;
    #pragma unroll
    for (int d = 1; d < 64; d <<= 1) sm += __shfl_xor(sm, d);
    __syncthreads();
    if (lane == 0) s_red[wid] = sm;
    __syncthreads();
    float den = 0.f;
    #pragma unroll
    for (int w = 0; w < 8; ++w) den += s_red[w];
    float inv = den > 0.f ? 1.f/den : 0.f;
    s_sc[t] = p * inv;
  }
  __syncthreads();

  // ---- L7: z = g1 @ eg_w2 + b2; msg += rcp(1+exp(-z)) * attn * nbr ----
  {
    uint4 gA[4][2];
    #pragma unroll
    for (int st = 0; st < 4; ++st) { gA[st][0] = loadA(R + st*16, 0); gA[st][1] = loadA(R + st*16, 1); }
    float attnR[16];
    #pragma unroll
    for (int q = 0; q < 16; ++q) attnR[q] = s_sc[R + (q>>2)*16 + l4*4 + (q&3)];

    for (int ct = 0; ct < 16; ++ct) {
      uint4 B0 = loadB(Weg2, ct, 0), B1 = loadB(Weg2, ct, 1);
      int col = ct*16 + l16;
      float bz = s_beg2[col];
      const float* nbrc = nbrT + (size_t)col*512 + R + l4*4;
      float msgp = 0.f;
      #pragma unroll
      for (int st = 0; st < 4; ++st) {
        f32x4 nv = *(const f32x4*)(nbrc + st*16);
        f32x4 c = {bz, bz, bz, bz};
        c = mfma_bf16(gA[st][0], B0, c);
        c = mfma_bf16(gA[st][1], B1, c);
        #pragma unroll
        for (int r = 0; r < 4; ++r) {
          float g = __builtin_amdgcn_rcpf(1.f + __expf(-c[r]));
          msgp += g * attnR[st*4 + r] * nv[r];
        }
      }
      msgp += __shfl_xor(msgp, 16);
      msgp += __shfl_xor(msgp, 32);
      if (lane < 16) s_msg[wid][ct*16 + lane] = msgp;
    }
  }
  __syncthreads();
  if (t < 256) {
    float s = 0.f;
    #pragma unroll
    for (int w = 0; w < 8; ++w) s += s_msg[w][t];
    ws[OFF_MSG + (size_t)(b*NN + i)*OO + t] = s;
  }
}

// ---------------------------------------------------------------------------
// k_out (MFMA): unchanged.
// ---------------------------------------------------------------------------
__global__ __launch_bounds__(256) void k_out(
    const float* __restrict__ cb_b1, const float* __restrict__ cb_b2,
    const float* __restrict__ ws, float* __restrict__ out)
{
  __shared__ __align__(16) unsigned char sA[16*1024];
  __shared__ __align__(16) unsigned char sT[16*512];
  const int t = threadIdx.x;
  const int g0 = blockIdx.x * 16;

  for (int idx = t; idx < 16*128; idx += 256) {
    int row = idx >> 7, kq = idx & 127;
    const float* src = (kq < 64)
        ? ws + OFF_SF  + (size_t)(g0 + row)*OO + kq*4
        : ws + OFF_MSG + (size_t)(g0 + row)*OO + (kq - 64)*4;
    float4 v = *(const float4*)src;
    uint2 p; p.x = pk2(v.x, v.y); p.y = pk2(v.z, v.w);
    *(uint2*)(sA + row*1024 + swzc(kq >> 1, row)*16 + (kq & 1)*8) = p;
  }
  __syncthreads();

  const int wid = t >> 6, lane = t & 63, l4 = lane >> 4, l16 = lane & 15;
  const unsigned char* W1 = (const unsigned char*)(ws + OFF_W1);
  const unsigned char* W2 = (const unsigned char*)(ws + OFF_W2);

  {
    uint4 af[16];
    #pragma unroll
    for (int f = 0; f < 16; ++f)
      af[f] = *(const uint4*)(sA + l16*1024 + swzc(l4 + 4*f, l16)*16);
    #pragma unroll
    for (int c = 0; c < 4; ++c) {
      int col = wid*64 + c*16 + l16;
      float bz = cb_b1[col];
      f32x4 acc = {bz, bz, bz, bz};
      #pragma unroll
      for (int f = 0; f < 16; ++f) {
        uint4 bfr = *(const uint4*)(W1 + (size_t)col*1024 + swzc(l4 + 4*f, col)*16);
        acc = mfma_bf16(af[f], bfr, acc);
      }
      #pragma unroll
      for (int r = 0; r < 4; ++r) {
        int row = l4*4 + r;
        *(unsigned short*)(sT + row*512 + swzc(col >> 3, row)*16 + (col & 7)*2)
            = f2bf(fmaxf(acc[r], 0.f));
      }
    }
  }
  __syncthreads();

  {
    uint4 tf[8];
    #pragma unroll
    for (int f = 0; f < 8; ++f)
      tf[f] = *(const uint4*)(sT + l16*512 + swzc(l4 + 4*f, l16)*16);
    #pragma unroll
    for (int c = 0; c < 4; ++c) {
      int col = wid*64 + c*16 + l16;
      float bz = cb_b2[col];
      f32x4 acc = {bz, bz, bz, bz};
      #pragma unroll
      for (int f = 0; f < 8; ++f) {
        uint4 bfr = *(const uint4*)(W2 + (size_t)col*512 + swzc(l4 + 4*f, col)*16);
        acc = mfma_bf16(tf[f], bfr, acc);
      }
      #pragma unroll
      for (int r = 0; r < 4; ++r)
        out[(size_t)(g0 + l4*4 + r)*OO + col] = acc[r];
    }
  }
}

extern "C" void kernel_launch(void* const* d_in, const int* in_sizes, int n_in,
                              void* d_out, int out_size, void* d_ws, size_t ws_size,
                              hipStream_t stream) {
  const float* x     = (const float*)d_in[0];
  const int*   adj   = (const int*)  d_in[1];
  const float* ef    = (const float*)d_in[2];
  const float* st_w  = (const float*)d_in[3];
  const float* st_b  = (const float*)d_in[4];
  const float* nt_w  = (const float*)d_in[5];
  const float* nt_b  = (const float*)d_in[6];
  const float* em_w1 = (const float*)d_in[7];
  const float* em_b1 = (const float*)d_in[8];
  const float* em_w2 = (const float*)d_in[9];
  const float* em_b2 = (const float*)d_in[10];
  const float* em_w3 = (const float*)d_in[11];
  const float* em_b3 = (const float*)d_in[12];
  const float* at_w1 = (const float*)d_in[13];
  const float* at_b1 = (const float*)d_in[14];
  const float* at_w2 = (const float*)d_in[15];
  const float* at_b2 = (const float*)d_in[16];
  const float* at_w3 = (const float*)d_in[17];
  const float* at_b3 = (const float*)d_in[18];
  const float* eg_w1 = (const float*)d_in[19];
  const float* eg_b1 = (const float*)d_in[20];
  const float* eg_w2 = (const float*)d_in[21];
  const float* eg_b2 = (const float*)d_in[22];
  const float* cb_w1 = (const float*)d_in[23];
  const float* cb_b1 = (const float*)d_in[24];
  const float* cb_w2 = (const float*)d_in[25];
  const float* cb_b2 = (const float*)d_in[26];
  float* ws  = (float*)d_ws;
  float* out = (float*)d_out;
  unsigned char* wimg = (unsigned char*)d_out;   // dead until k_out overwrites

  k_prep_edge<<<dim3(120), dim3(256), 0, stream>>>(em_w1, em_w2, em_w3, at_w1, at_w2, eg_w1, eg_w2, wimg);
  k_prep_node<<<dim3(88), dim3(256), 0, stream>>>(st_w, nt_w, at_w1, eg_w1, ws);
  k_node<<<dim3(11, 16), dim3(256), 0, stream>>>(x, st_b, nt_b, ws);
  k_edge<<<dim3(NN, BB), dim3(512), 0, stream>>>(adj, ef, wimg,
      em_b1, em_b2, em_b3, at_b1, at_b2, at_w3, at_b3, eg_b1, eg_b2, ws);
  k_prep_out<<<dim3(96), dim3(256), 0, stream>>>(cb_w1, cb_w2, ws);
  k_out<<<dim3(64), dim3(256), 0, stream>>>(cb_b1, cb_b2, ws, out);
}

// Round 6
// 171.861 us; speedup vs baseline: 4.8813x; 1.0182x over previous
//
#include <hip/hip_runtime.h>

#define BB 2
#define NN 512
#define CC 256
#define OO 256
#define EE 18

// workspace layout (float offsets)
#define OFF_SF   0
#define OFF_NBR  (BB*NN*OO)
#define OFF_AI   (OFF_NBR + BB*NN*OO)
#define OFF_AJ   (OFF_AI + BB*NN*64)
#define OFF_EGX  (OFF_AJ + BB*NN*64)
#define OFF_MSG  (OFF_EGX + BB*NN*64)
// NOTE: NBR/AJ/EGX are stored TRANSPOSED: [b][col][row]
// aliased weight-staging regions (lifetime-disjoint):
// WN in MSG region (prep -> k_node, clobbered later by k_edge MSG writes).
// W1/W2 in AI/AJ regions (prep_out runs AFTER k_edge).
// Edge-weight image lives in d_out (dead until k_out overwrites it).
#define OFF_WN   OFF_MSG
#define OFF_W1   OFF_AI
#define OFF_W2   OFF_AJ

typedef float f32x4 __attribute__((ext_vector_type(4)));
typedef __bf16 bf16x8 __attribute__((ext_vector_type(8)));

__device__ __forceinline__ unsigned short f2bf(float f) {
  unsigned u = __float_as_uint(f);
  u += 0x7fffu + ((u >> 16) & 1u);          // RNE
  return (unsigned short)(u >> 16);
}
__device__ __forceinline__ unsigned pk2(float a, float b) {
  return (unsigned)f2bf(a) | ((unsigned)f2bf(b) << 16);
}
__device__ __forceinline__ int swzc(int chunk, int row) {
  return (chunk & ~7) | ((chunk ^ row) & 7);
}

__device__ __forceinline__ f32x4 mfma_bf16(uint4 a, uint4 b, f32x4 c) {
  return __builtin_amdgcn_mfma_f32_16x16x32_bf16(
      __builtin_bit_cast(bf16x8, a), __builtin_bit_cast(bf16x8, b), c, 0, 0, 0);
}

// ---------------------------------------------------------------------------
// k_prep_w: merged front-end weight prep.
// bid<120: edge-MLP weight image (transposed bf16, chunk-swizzled) into d_out.
//   regions (byte offsets): em1 0 | em2 8192 | em3 16384 | at1e 20480 |
//                           at2 28672 | eg1e 32768 | eg2 40960 | end 73728
// bid>=120: node weights -> Wnode [704 cols][256 k] bf16 (in ws MSG region).
// ---------------------------------------------------------------------------
__global__ __launch_bounds__(256) void k_prep_w(
    const float* __restrict__ em_w1, const float* __restrict__ em_w2,
    const float* __restrict__ em_w3, const float* __restrict__ at_w1,
    const float* __restrict__ at_w2, const float* __restrict__ eg_w1,
    const float* __restrict__ eg_w2,
    const float* __restrict__ st_w,  const float* __restrict__ nt_w,
    unsigned char* __restrict__ img, float* __restrict__ ws)
{
  int bid = blockIdx.x;
  if (bid < 120) {
    int idx = bid * 256 + threadIdx.x;   // 0..30719
    const float* src; int KV, RO, k, l, ldw;
    if (idx < 2048)       { src = em_w1;          KV = 18; RO = 0;     k = idx>>6;  l = idx&63;  ldw = 64; }
    else if (idx < 6144)  { src = em_w2;          KV = 64; RO = 8192;  int e = idx-2048;  k = e>>6; l = e&63;  ldw = 64; }
    else if (idx < 8192)  { src = em_w3;          KV = 64; RO = 16384; int e = idx-6144;  k = e>>5; l = e&31;  ldw = 32; }
    else if (idx < 10240) { src = at_w1 + 512*64; KV = 32; RO = 20480; int e = idx-8192;  k = e>>6; l = e&63;  ldw = 64; }
    else if (idx < 12288) { src = at_w2;          KV = 64; RO = 28672; int e = idx-10240; k = e>>5; l = e&31;  ldw = 32; }
    else if (idx < 14336) { src = eg_w1 + 256*64; KV = 32; RO = 32768; int e = idx-12288; k = e>>6; l = e&63;  ldw = 64; }
    else                  { src = eg_w2;          KV = 64; RO = 40960; int e = idx-14336; k = e>>8; l = e&255; ldw = 256; }
    float v = (k < KV) ? src[(size_t)k*ldw + l] : 0.f;
    *(unsigned short*)(img + RO + l*128 + ((((k>>3) ^ (l&7))) << 4) + ((k&7) << 1)) = f2bf(v);
  } else {
    unsigned char* dst = (unsigned char*)(ws + OFF_WN);
    int idx = (bid - 120) * 256 + threadIdx.x;       // 704*32 = 22528
    int col = idx >> 5, ch = idx & 31;
    const float* src; int ld, c;
    if (col < 256)      { src = st_w;           ld = 256; c = col; }
    else if (col < 512) { src = nt_w;           ld = 256; c = col - 256; }
    else if (col < 576) { src = at_w1;          ld = 64;  c = col - 512; }
    else if (col < 640) { src = at_w1 + 256*64; ld = 64;  c = col - 576; }
    else                { src = eg_w1;          ld = 64;  c = col - 640; }
    float e[8];
    #pragma unroll
    for (int q = 0; q < 8; ++q) e[q] = src[(size_t)(ch*8+q)*ld + c];
    uint4 v = make_uint4(pk2(e[0],e[1]), pk2(e[2],e[3]), pk2(e[4],e[5]), pk2(e[6],e[7]));
    *(uint4*)(dst + (size_t)col*512 + swzc(ch, col)*16) = v;
  }
}

// ---------------------------------------------------------------------------
// prep_out: cb_w1 -> W1 [256 cols][512 k] bf16; cb_w2 -> W2 [256][256].
// ---------------------------------------------------------------------------
__global__ __launch_bounds__(256) void k_prep_out(
    const float* __restrict__ cb_w1, const float* __restrict__ cb_w2,
    float* __restrict__ ws)
{
  int bid = blockIdx.x;
  if (bid < 64) {
    unsigned char* dst = (unsigned char*)(ws + OFF_W1);
    int idx = bid * 256 + threadIdx.x;
    int col = idx >> 6, ch = idx & 63;
    float e[8];
    #pragma unroll
    for (int q = 0; q < 8; ++q) e[q] = cb_w1[(size_t)(ch*8+q)*256 + col];
    uint4 v = make_uint4(pk2(e[0],e[1]), pk2(e[2],e[3]), pk2(e[4],e[5]), pk2(e[6],e[7]));
    *(uint4*)(dst + (size_t)col*1024 + swzc(ch, col)*16) = v;
  } else {
    unsigned char* dst = (unsigned char*)(ws + OFF_W2);
    int idx = (bid - 64) * 256 + threadIdx.x;
    int col = idx >> 5, ch = idx & 31;
    float e[8];
    #pragma unroll
    for (int q = 0; q < 8; ++q) e[q] = cb_w2[(size_t)(ch*8+q)*256 + col];
    uint4 v = make_uint4(pk2(e[0],e[1]), pk2(e[2],e[3]), pk2(e[4],e[5]), pk2(e[6],e[7]));
    *(uint4*)(dst + (size_t)col*512 + swzc(ch, col)*16) = v;
  }
}

// ---------------------------------------------------------------------------
// k_node (MFMA): C[1024 x 704] = x[1024 x 256] @ Wnode.
// SF row-major+bias; NBR^T/AJ^T/EGX^T stored [b][col][row] via float4 stores.
// ---------------------------------------------------------------------------
__global__ __launch_bounds__(256) void k_node(
    const float* __restrict__ x,
    const float* __restrict__ st_b, const float* __restrict__ nt_b,
    float* __restrict__ ws)
{
  __shared__ __align__(16) unsigned char sA[64*512];   // 32 KB
  const int t = threadIdx.x;
  const int c0 = blockIdx.x * 64, g0 = blockIdx.y * 64;

  for (int idx = t; idx < 64*64; idx += 256) {
    int row = idx >> 6, kq = idx & 63;
    float4 v = *(const float4*)(x + (size_t)(g0 + row)*CC + kq*4);
    uint2 p; p.x = pk2(v.x, v.y); p.y = pk2(v.z, v.w);
    *(uint2*)(sA + row*512 + swzc(kq >> 1, row)*16 + (kq & 1)*8) = p;
  }
  __syncthreads();

  const int wid = t >> 6, lane = t & 63, l4 = lane >> 4, l16 = lane & 15;
  const unsigned char* WN = (const unsigned char*)(ws + OFF_WN);

  uint4 af[8];
  {
    int row = wid*16 + l16;
    #pragma unroll
    for (int f = 0; f < 8; ++f)
      af[f] = *(const uint4*)(sA + row*512 + swzc(l4 + 4*f, row)*16);
  }

  #pragma unroll
  for (int ct = 0; ct < 4; ++ct) {
    int gcol = c0 + ct*16 + l16;
    f32x4 acc = {0.f, 0.f, 0.f, 0.f};
    #pragma unroll
    for (int f = 0; f < 8; ++f) {
      uint4 bfr = *(const uint4*)(WN + (size_t)gcol*512 + swzc(l4 + 4*f, gcol)*16);
      acc = mfma_bf16(af[f], bfr, acc);
    }
    int gr0 = g0 + wid*16 + l4*4;
    int bb = gr0 >> 9, n0 = gr0 & 511;
    if (gcol < 256) {
      float bz = st_b[gcol];
      #pragma unroll
      for (int r = 0; r < 4; ++r) ws[OFF_SF + (size_t)(gr0+r)*OO + gcol] = acc[r] + bz;
    } else if (gcol < 512) {
      int c = gcol - 256;
      float bz = nt_b[c];
      f32x4 v = {acc[0]+bz, acc[1]+bz, acc[2]+bz, acc[3]+bz};
      *(f32x4*)(ws + OFF_NBR + ((size_t)bb*256 + c)*512 + n0) = v;
    } else if (gcol < 576) {
      #pragma unroll
      for (int r = 0; r < 4; ++r) ws[OFF_AI + (size_t)(gr0+r)*64 + (gcol-512)] = acc[r];
    } else if (gcol < 640) {
      int c = gcol - 576;
      *(f32x4*)(ws + OFF_AJ + ((size_t)bb*64 + c)*512 + n0) = acc;
    } else {
      int c = gcol - 640;
      *(f32x4*)(ws + OFF_EGX + ((size_t)bb*64 + c)*512 + n0) = acc;
    }
  }
}

// ---------------------------------------------------------------------------
// k_edge: fused per-row edge kernel, full-MFMA. 1 block per (i,b). 512 thr.
// Weights read directly from the L2-hot pre-swizzled global image.
// Register diet (attnR hoist dropped, maskf in reg, no s_maskf LDS) targets
// total regs <=128/wave -> 4 waves/SIMD -> 2 blocks/CU with ~78 KB LDS.
// ---------------------------------------------------------------------------
__global__ __launch_bounds__(512, 2) void k_edge(
    const int*   __restrict__ adj,
    const float* __restrict__ ef_g,
    const unsigned char* __restrict__ wimg,
    const float* __restrict__ em_b1g, const float* __restrict__ em_b2g,
    const float* __restrict__ em_b3g,
    const float* __restrict__ at_b1g, const float* __restrict__ at_b2g,
    const float* __restrict__ at_w3g, const float* __restrict__ at_b3g,
    const float* __restrict__ eg_b1g, const float* __restrict__ eg_b2g,
    float* __restrict__ ws)
{
  __shared__ __align__(16) unsigned char s_act[512*128];   // 64 KB activation bounce
  __shared__ float s_bem1[64], s_bem2[64], s_bem3[32];
  __shared__ float s_t1init[64], s_bat2[32], s_w3[32];
  __shared__ float s_beg1[64], s_beg2[256];
  __shared__ __align__(16) float s_sc[512];
  __shared__ float s_red[8];
  __shared__ float s_msg[8][256];

  const int t = threadIdx.x;
  const int i = blockIdx.x, b = blockIdx.y;
  const int wid = t >> 6, lane = t & 63, l4 = lane >> 4, l16 = lane & 15;
  const int R = wid * 64;

  const unsigned char* Wem1 = wimg;
  const unsigned char* Wem2 = wimg + 8192;
  const unsigned char* Wem3 = wimg + 16384;
  const unsigned char* Wat1 = wimg + 20480;
  const unsigned char* Wat2 = wimg + 28672;
  const unsigned char* Weg1 = wimg + 32768;
  const unsigned char* Weg2 = wimg + 40960;

  if (t < 64) {
    s_bem1[t]   = em_b1g[t];
    s_bem2[t]   = em_b2g[t];
    s_t1init[t] = ws[OFF_AI + (size_t)(b*NN + i)*64 + t] + at_b1g[t];
    s_beg1[t]   = eg_b1g[t];
  } else if (t < 96)  { s_bem3[t-64]  = em_b3g[t-64]; }
  else if (t < 128)   { s_bat2[t-96]  = at_b2g[t-96]; }
  else if (t < 160)   { s_w3[t-128]   = at_w3g[t-128]; }
  if (t < 256) s_beg2[t] = eg_b2g[t];
  const float atb3 = at_b3g[0];

  const float maskf = adj[(size_t)(b*NN + i)*NN + t] > 0 ? 1.f : 0.f;  // reg, own-j only

  // stage ef row (pad 18 -> 32, bf16, swizzled)
  {
    const int j = t;
    const float* efp = ef_g + ((size_t)(b*NN + i)*NN + j) * EE;
    float e[32];
    #pragma unroll
    for (int k = 0; k < 9; ++k) { float2 v2 = *(const float2*)(efp + 2*k); e[2*k] = v2.x; e[2*k+1] = v2.y; }
    #pragma unroll
    for (int k = EE; k < 32; ++k) e[k] = 0.f;
    #pragma unroll
    for (int c = 0; c < 4; ++c) {
      uint4 u = make_uint4(pk2(e[c*8+0],e[c*8+1]), pk2(e[c*8+2],e[c*8+3]),
                           pk2(e[c*8+4],e[c*8+5]), pk2(e[c*8+6],e[c*8+7]));
      *(uint4*)(s_act + j*128 + ((c ^ (j & 7)) << 4)) = u;
    }
  }
  __syncthreads();

  auto loadA = [&](int rb, int f) -> uint4 {
    int rw = rb + l16;
    return *(const uint4*)(s_act + rw*128 + (((l4 + 4*f) ^ (rw & 7)) << 4));
  };
  auto loadB = [&](const unsigned char* w, int ct, int f) -> uint4 {
    int rw = ct*16 + l16;
    return *(const uint4*)(w + rw*128 + (((l4 + 4*f) ^ (rw & 7)) << 4));
  };
  auto storeCR = [&](int rb, int ct, const f32x4& c) {
    int col = ct*16 + l16;
    #pragma unroll
    for (int r = 0; r < 4; ++r) {
      int rw = rb + l4*4 + r;
      *(unsigned short*)(s_act + rw*128 + (((col >> 3) ^ (rw & 7)) << 4) + ((col & 7) << 1))
          = f2bf(fmaxf(c[r], 0.f));
    }
  };

  const float* ajT  = ws + OFF_AJ  + (size_t)b*64*512;    // [col][row]
  const float* egT  = ws + OFF_EGX + (size_t)b*64*512;    // [col][row]
  const float* nbrT = ws + OFF_NBR + (size_t)b*256*512;   // [col][row]

  uint4 peA[4];

  // ---- L1: ef(K32) -> h1(64) ----
  {
    uint4 B[4];
    #pragma unroll
    for (int ct = 0; ct < 4; ++ct) B[ct] = loadB(Wem1, ct, 0);
    #pragma unroll
    for (int st = 0; st < 4; ++st) {
      int rb = R + st*16;
      uint4 a = loadA(rb, 0);
      #pragma unroll
      for (int ct = 0; ct < 4; ++ct) {
        float bz = s_bem1[ct*16 + l16];
        f32x4 c = {bz, bz, bz, bz};
        c = mfma_bf16(a, B[ct], c);
        storeCR(rb, ct, c);
      }
    }
  }
  // ---- L2: h1(K64) -> h2(64) ----
  {
    uint4 B[4][2];
    #pragma unroll
    for (int ct = 0; ct < 4; ++ct) { B[ct][0] = loadB(Wem2, ct, 0); B[ct][1] = loadB(Wem2, ct, 1); }
    #pragma unroll
    for (int st = 0; st < 4; ++st) {
      int rb = R + st*16;
      uint4 a0 = loadA(rb, 0), a1 = loadA(rb, 1);
      #pragma unroll
      for (int ct = 0; ct < 4; ++ct) {
        float bz = s_bem2[ct*16 + l16];
        f32x4 c = {bz, bz, bz, bz};
        c = mfma_bf16(a0, B[ct][0], c);
        c = mfma_bf16(a1, B[ct][1], c);
        storeCR(rb, ct, c);
      }
    }
  }
  // ---- L3: h2(K64) -> pe(32); keep pe A-frags in registers ----
  {
    uint4 B[2][2];
    #pragma unroll
    for (int ct = 0; ct < 2; ++ct) { B[ct][0] = loadB(Wem3, ct, 0); B[ct][1] = loadB(Wem3, ct, 1); }
    #pragma unroll
    for (int st = 0; st < 4; ++st) {
      int rb = R + st*16;
      uint4 a0 = loadA(rb, 0), a1 = loadA(rb, 1);
      #pragma unroll
      for (int ct = 0; ct < 2; ++ct) {
        float bz = s_bem3[ct*16 + l16];
        f32x4 c = {bz, bz, bz, bz};
        c = mfma_bf16(a0, B[ct][0], c);
        c = mfma_bf16(a1, B[ct][1], c);
        storeCR(rb, ct, c);
      }
      peA[st] = loadA(rb, 0);
    }
  }
  // ---- L4a: t1 = relu(a_i + a_j + b1 + pe @ at_w1e) ----
  {
    uint4 B[4];
    #pragma unroll
    for (int ct = 0; ct < 4; ++ct) B[ct] = loadB(Wat1, ct, 0);
    #pragma unroll
    for (int st = 0; st < 4; ++st) {
      int rb = R + st*16;
      #pragma unroll
      for (int ct = 0; ct < 4; ++ct) {
        int col = ct*16 + l16;
        f32x4 av = *(const f32x4*)(ajT + (size_t)col*512 + rb + l4*4);
        float ti = s_t1init[col];
        f32x4 c = {ti + av[0], ti + av[1], ti + av[2], ti + av[3]};
        c = mfma_bf16(peA[st], B[ct], c);
        storeCR(rb, ct, c);
      }
    }
  }
  // ---- L5: t2 = relu(t1 @ at_w2 + b2); score = t2 . w3 + b3 ----
  {
    uint4 B[2][2];
    #pragma unroll
    for (int ct = 0; ct < 2; ++ct) { B[ct][0] = loadB(Wat2, ct, 0); B[ct][1] = loadB(Wat2, ct, 1); }
    #pragma unroll
    for (int st = 0; st < 4; ++st) {
      int rb = R + st*16;
      uint4 a0 = loadA(rb, 0), a1 = loadA(rb, 1);
      float b0 = s_bat2[l16], b1v = s_bat2[16 + l16];
      f32x4 c0 = {b0, b0, b0, b0}, c1 = {b1v, b1v, b1v, b1v};
      c0 = mfma_bf16(a0, B[0][0], c0); c0 = mfma_bf16(a1, B[0][1], c0);
      c1 = mfma_bf16(a0, B[1][0], c1); c1 = mfma_bf16(a1, B[1][1], c1);
      float w3a = s_w3[l16], w3b = s_w3[16 + l16];
      #pragma unroll
      for (int r = 0; r < 4; ++r) {
        float val = fmaxf(c0[r], 0.f)*w3a + fmaxf(c1[r], 0.f)*w3b;
        val += __shfl_xor(val, 1); val += __shfl_xor(val, 2);
        val += __shfl_xor(val, 4); val += __shfl_xor(val, 8);
        if (l16 == 0) s_sc[rb + l4*4 + r] = val + atb3;
      }
    }
  }
  // ---- L4b: g1 = relu(eg_x_j + eg_b1 + pe @ eg_w1e) -> s_act ----
  {
    uint4 B[4];
    #pragma unroll
    for (int ct = 0; ct < 4; ++ct) B[ct] = loadB(Weg1, ct, 0);
    #pragma unroll
    for (int st = 0; st < 4; ++st) {
      int rb = R + st*16;
      #pragma unroll
      for (int ct = 0; ct < 4; ++ct) {
        int col = ct*16 + l16;
        f32x4 ev = *(const f32x4*)(egT + (size_t)col*512 + rb + l4*4);
        float bg = s_beg1[col];
        f32x4 c = {bg + ev[0], bg + ev[1], bg + ev[2], bg + ev[3]};
        c = mfma_bf16(peA[st], B[ct], c);
        storeCR(rb, ct, c);
      }
    }
  }
  __syncthreads();

  // ---------------- masked softmax over j ----------------
  {
    float v  = maskf > 0.f ? s_sc[t] : -1e9f;
    float m = v;
    #pragma unroll
    for (int d = 1; d < 64; d <<= 1) m = fmaxf(m, __shfl_xor(m, d));
    if (lane == 0) s_red[wid] = m;
    __syncthreads();
    float mx = s_red[0];
    #pragma unroll
    for (int w = 1; w < 8; ++w) mx = fmaxf(mx, s_red[w]);
    float p = maskf > 0.f ? __expf(v - mx) : 0.f;
    float sm = p;
    #pragma unroll
    for (int d = 1; d < 64; d <<= 1) sm += __shfl_xor(sm, d);
    __syncthreads();
    if (lane == 0) s_red[wid] = sm;
    __syncthreads();
    float den = 0.f;
    #pragma unroll
    for (int w = 0; w < 8; ++w) den += s_red[w];
    float inv = den > 0.f ? 1.f/den : 0.f;
    s_sc[t] = p * inv;
  }
  __syncthreads();

  // ---- L7: z = g1 @ eg_w2 + b2; msg += rcp(1+exp(-z)) * attn * nbr ----
  {
    uint4 gA[4][2];
    #pragma unroll
    for (int st = 0; st < 4; ++st) { gA[st][0] = loadA(R + st*16, 0); gA[st][1] = loadA(R + st*16, 1); }

    for (int ct = 0; ct < 16; ++ct) {
      uint4 B0 = loadB(Weg2, ct, 0), B1 = loadB(Weg2, ct, 1);
      int col = ct*16 + l16;
      float bz = s_beg2[col];
      const float* nbrc = nbrT + (size_t)col*512 + R + l4*4;
      float msgp = 0.f;
      #pragma unroll
      for (int st = 0; st < 4; ++st) {
        f32x4 nv = *(const f32x4*)(nbrc + st*16);
        f32x4 at = *(const f32x4*)(&s_sc[R + st*16 + l4*4]);
        f32x4 c = {bz, bz, bz, bz};
        c = mfma_bf16(gA[st][0], B0, c);
        c = mfma_bf16(gA[st][1], B1, c);
        #pragma unroll
        for (int r = 0; r < 4; ++r) {
          float g = __builtin_amdgcn_rcpf(1.f + __expf(-c[r]));
          msgp += g * at[r] * nv[r];
        }
      }
      msgp += __shfl_xor(msgp, 16);
      msgp += __shfl_xor(msgp, 32);
      if (lane < 16) s_msg[wid][ct*16 + lane] = msgp;
    }
  }
  __syncthreads();
  if (t < 256) {
    float s = 0.f;
    #pragma unroll
    for (int w = 0; w < 8; ++w) s += s_msg[w][t];
    ws[OFF_MSG + (size_t)(b*NN + i)*OO + t] = s;
  }
}

// ---------------------------------------------------------------------------
// k_out (MFMA): unchanged.
// ---------------------------------------------------------------------------
__global__ __launch_bounds__(256) void k_out(
    const float* __restrict__ cb_b1, const float* __restrict__ cb_b2,
    const float* __restrict__ ws, float* __restrict__ out)
{
  __shared__ __align__(16) unsigned char sA[16*1024];
  __shared__ __align__(16) unsigned char sT[16*512];
  const int t = threadIdx.x;
  const int g0 = blockIdx.x * 16;

  for (int idx = t; idx < 16*128; idx += 256) {
    int row = idx >> 7, kq = idx & 127;
    const float* src = (kq < 64)
        ? ws + OFF_SF  + (size_t)(g0 + row)*OO + kq*4
        : ws + OFF_MSG + (size_t)(g0 + row)*OO + (kq - 64)*4;
    float4 v = *(const float4*)src;
    uint2 p; p.x = pk2(v.x, v.y); p.y = pk2(v.z, v.w);
    *(uint2*)(sA + row*1024 + swzc(kq >> 1, row)*16 + (kq & 1)*8) = p;
  }
  __syncthreads();

  const int wid = t >> 6, lane = t & 63, l4 = lane >> 4, l16 = lane & 15;
  const unsigned char* W1 = (const unsigned char*)(ws + OFF_W1);
  const unsigned char* W2 = (const unsigned char*)(ws + OFF_W2);

  {
    uint4 af[16];
    #pragma unroll
    for (int f = 0; f < 16; ++f)
      af[f] = *(const uint4*)(sA + l16*1024 + swzc(l4 + 4*f, l16)*16);
    #pragma unroll
    for (int c = 0; c < 4; ++c) {
      int col = wid*64 + c*16 + l16;
      float bz = cb_b1[col];
      f32x4 acc = {bz, bz, bz, bz};
      #pragma unroll
      for (int f = 0; f < 16; ++f) {
        uint4 bfr = *(const uint4*)(W1 + (size_t)col*1024 + swzc(l4 + 4*f, col)*16);
        acc = mfma_bf16(af[f], bfr, acc);
      }
      #pragma unroll
      for (int r = 0; r < 4; ++r) {
        int row = l4*4 + r;
        *(unsigned short*)(sT + row*512 + swzc(col >> 3, row)*16 + (col & 7)*2)
            = f2bf(fmaxf(acc[r], 0.f));
      }
    }
  }
  __syncthreads();

  {
    uint4 tf[8];
    #pragma unroll
    for (int f = 0; f < 8; ++f)
      tf[f] = *(const uint4*)(sT + l16*512 + swzc(l4 + 4*f, l16)*16);
    #pragma unroll
    for (int c = 0; c < 4; ++c) {
      int col = wid*64 + c*16 + l16;
      float bz = cb_b2[col];
      f32x4 acc = {bz, bz, bz, bz};
      #pragma unroll
      for (int f = 0; f < 8; ++f) {
        uint4 bfr = *(const uint4*)(W2 + (size_t)col*512 + swzc(l4 + 4*f, col)*16);
        acc = mfma_bf16(tf[f], bfr, acc);
      }
      #pragma unroll
      for (int r = 0; r < 4; ++r)
        out[(size_t)(g0 + l4*4 + r)*OO + col] = acc[r];
    }
  }
}

extern "C" void kernel_launch(void* const* d_in, const int* in_sizes, int n_in,
                              void* d_out, int out_size, void* d_ws, size_t ws_size,
                              hipStream_t stream) {
  const float* x     = (const float*)d_in[0];
  const int*   adj   = (const int*)  d_in[1];
  const float* ef    = (const float*)d_in[2];
  const float* st_w  = (const float*)d_in[3];
  const float* st_b  = (const float*)d_in[4];
  const float* nt_w  = (const float*)d_in[5];
  const float* nt_b  = (const float*)d_in[6];
  const float* em_w1 = (const float*)d_in[7];
  const float* em_b1 = (const float*)d_in[8];
  const float* em_w2 = (const float*)d_in[9];
  const float* em_b2 = (const float*)d_in[10];
  const float* em_w3 = (const float*)d_in[11];
  const float* em_b3 = (const float*)d_in[12];
  const float* at_w1 = (const float*)d_in[13];
  const float* at_b1 = (const float*)d_in[14];
  const float* at_w2 = (const float*)d_in[15];
  const float* at_b2 = (const float*)d_in[16];
  const float* at_w3 = (const float*)d_in[17];
  const float* at_b3 = (const float*)d_in[18];
  const float* eg_w1 = (const float*)d_in[19];
  const float* eg_b1 = (const float*)d_in[20];
  const float* eg_w2 = (const float*)d_in[21];
  const float* eg_b2 = (const float*)d_in[22];
  const float* cb_w1 = (const float*)d_in[23];
  const float* cb_b1 = (const float*)d_in[24];
  const float* cb_w2 = (const float*)d_in[25];
  const float* cb_b2 = (const float*)d_in[26];
  float* ws  = (float*)d_ws;
  float* out = (float*)d_out;
  unsigned char* wimg = (unsigned char*)d_out;   // dead until k_out overwrites

  k_prep_w<<<dim3(208), dim3(256), 0, stream>>>(em_w1, em_w2, em_w3, at_w1, at_w2,
      eg_w1, eg_w2, st_w, nt_w, wimg, ws);
  k_node<<<dim3(11, 16), dim3(256), 0, stream>>>(x, st_b, nt_b, ws);
  k_edge<<<dim3(NN, BB), dim3(512), 0, stream>>>(adj, ef, wimg,
      em_b1, em_b2, em_b3, at_b1, at_b2, at_w3, at_b3, eg_b1, eg_b2, ws);
  k_prep_out<<<dim3(96), dim3(256), 0, stream>>>(cb_w1, cb_w2, ws);
  k_out<<<dim3(64), dim3(256), 0, stream>>>(cb_b1, cb_b2, ws, out);
}

// Round 7
// 140.891 us; speedup vs baseline: 5.9543x; 1.2198x over previous
//
#include <hip/hip_runtime.h>

#define BB 2
#define NN 512
#define CC 256
#define OO 256
#define EE 18

// workspace layout (float offsets)
#define OFF_SF   0
#define OFF_NBR  (BB*NN*OO)
#define OFF_AI   (OFF_NBR + BB*NN*OO)
#define OFF_AJ   (OFF_AI + BB*NN*64)
#define OFF_EGX  (OFF_AJ + BB*NN*64)
#define OFF_MSG  (OFF_EGX + BB*NN*64)
// NBR stored TRANSPOSED [b][col][row] (for L7); AJ/EGX/AI/SF row-major (for swapped inits).
// aliased weight-staging regions (lifetime-disjoint):
// WN in MSG region (prep -> k_node, clobbered later by k_edge MSG writes).
// W1/W2 in AI/AJ regions (prep_out runs AFTER k_edge).
// Edge-weight image lives in d_out (dead until k_out overwrites it).
#define OFF_WN   OFF_MSG
#define OFF_W1   OFF_AI
#define OFF_W2   OFF_AJ

typedef float f32x4 __attribute__((ext_vector_type(4)));
typedef __bf16 bf16x8 __attribute__((ext_vector_type(8)));

__device__ __forceinline__ unsigned short f2bf(float f) {
  unsigned u = __float_as_uint(f);
  u += 0x7fffu + ((u >> 16) & 1u);          // RNE
  return (unsigned short)(u >> 16);
}
__device__ __forceinline__ unsigned pk2(float a, float b) {
  return (unsigned)f2bf(a) | ((unsigned)f2bf(b) << 16);
}
__device__ __forceinline__ unsigned cvtpk(float a, float b) {
  unsigned r;
  asm("v_cvt_pk_bf16_f32 %0, %1, %2" : "=v"(r) : "v"(a), "v"(b));
  return r;   // lo = bf16(a), hi = bf16(b)
}
__device__ __forceinline__ int swzc(int chunk, int row) {
  return (chunk & ~7) | ((chunk ^ row) & 7);
}

__device__ __forceinline__ f32x4 mfma_bf16(uint4 a, uint4 b, f32x4 c) {
  return __builtin_amdgcn_mfma_f32_16x16x32_bf16(
      __builtin_bit_cast(bf16x8, a), __builtin_bit_cast(bf16x8, b), c, 0, 0, 0);
}

// ---------------------------------------------------------------------------
// k_prep_w: merged front-end weight prep (edge image -> d_out, node -> WN).
// ---------------------------------------------------------------------------
__global__ __launch_bounds__(256) void k_prep_w(
    const float* __restrict__ em_w1, const float* __restrict__ em_w2,
    const float* __restrict__ em_w3, const float* __restrict__ at_w1,
    const float* __restrict__ at_w2, const float* __restrict__ eg_w1,
    const float* __restrict__ eg_w2,
    const float* __restrict__ st_w,  const float* __restrict__ nt_w,
    unsigned char* __restrict__ img, float* __restrict__ ws)
{
  int bid = blockIdx.x;
  if (bid < 120) {
    int idx = bid * 256 + threadIdx.x;   // 0..30719
    const float* src; int KV, RO, k, l, ldw;
    if (idx < 2048)       { src = em_w1;          KV = 18; RO = 0;     k = idx>>6;  l = idx&63;  ldw = 64; }
    else if (idx < 6144)  { src = em_w2;          KV = 64; RO = 8192;  int e = idx-2048;  k = e>>6; l = e&63;  ldw = 64; }
    else if (idx < 8192)  { src = em_w3;          KV = 64; RO = 16384; int e = idx-6144;  k = e>>5; l = e&31;  ldw = 32; }
    else if (idx < 10240) { src = at_w1 + 512*64; KV = 32; RO = 20480; int e = idx-8192;  k = e>>6; l = e&63;  ldw = 64; }
    else if (idx < 12288) { src = at_w2;          KV = 64; RO = 28672; int e = idx-10240; k = e>>5; l = e&31;  ldw = 32; }
    else if (idx < 14336) { src = eg_w1 + 256*64; KV = 32; RO = 32768; int e = idx-12288; k = e>>6; l = e&63;  ldw = 64; }
    else                  { src = eg_w2;          KV = 64; RO = 40960; int e = idx-14336; k = e>>8; l = e&255; ldw = 256; }
    float v = (k < KV) ? src[(size_t)k*ldw + l] : 0.f;
    *(unsigned short*)(img + RO + l*128 + ((((k>>3) ^ (l&7))) << 4) + ((k&7) << 1)) = f2bf(v);
  } else {
    unsigned char* dst = (unsigned char*)(ws + OFF_WN);
    int idx = (bid - 120) * 256 + threadIdx.x;       // 704*32 = 22528
    int col = idx >> 5, ch = idx & 31;
    const float* src; int ld, c;
    if (col < 256)      { src = st_w;           ld = 256; c = col; }
    else if (col < 512) { src = nt_w;           ld = 256; c = col - 256; }
    else if (col < 576) { src = at_w1;          ld = 64;  c = col - 512; }
    else if (col < 640) { src = at_w1 + 256*64; ld = 64;  c = col - 576; }
    else                { src = eg_w1;          ld = 64;  c = col - 640; }
    float e[8];
    #pragma unroll
    for (int q = 0; q < 8; ++q) e[q] = src[(size_t)(ch*8+q)*ld + c];
    uint4 v = make_uint4(pk2(e[0],e[1]), pk2(e[2],e[3]), pk2(e[4],e[5]), pk2(e[6],e[7]));
    *(uint4*)(dst + (size_t)col*512 + swzc(ch, col)*16) = v;
  }
}

// ---------------------------------------------------------------------------
// prep_out: cb_w1 -> W1 [256 cols][512 k] bf16; cb_w2 -> W2 [256][256].
// ---------------------------------------------------------------------------
__global__ __launch_bounds__(256) void k_prep_out(
    const float* __restrict__ cb_w1, const float* __restrict__ cb_w2,
    float* __restrict__ ws)
{
  int bid = blockIdx.x;
  if (bid < 64) {
    unsigned char* dst = (unsigned char*)(ws + OFF_W1);
    int idx = bid * 256 + threadIdx.x;
    int col = idx >> 6, ch = idx & 63;
    float e[8];
    #pragma unroll
    for (int q = 0; q < 8; ++q) e[q] = cb_w1[(size_t)(ch*8+q)*256 + col];
    uint4 v = make_uint4(pk2(e[0],e[1]), pk2(e[2],e[3]), pk2(e[4],e[5]), pk2(e[6],e[7]));
    *(uint4*)(dst + (size_t)col*1024 + swzc(ch, col)*16) = v;
  } else {
    unsigned char* dst = (unsigned char*)(ws + OFF_W2);
    int idx = (bid - 64) * 256 + threadIdx.x;
    int col = idx >> 5, ch = idx & 31;
    float e[8];
    #pragma unroll
    for (int q = 0; q < 8; ++q) e[q] = cb_w2[(size_t)(ch*8+q)*256 + col];
    uint4 v = make_uint4(pk2(e[0],e[1]), pk2(e[2],e[3]), pk2(e[4],e[5]), pk2(e[6],e[7]));
    *(uint4*)(dst + (size_t)col*512 + swzc(ch, col)*16) = v;
  }
}

// ---------------------------------------------------------------------------
// k_node (MFMA, swapped operands): thread holds 1 node-row x 4 consecutive
// cols -> float4 epilogue stores (SF/AI/AJ/EGX row-major; NBR^T scalar x4).
// ---------------------------------------------------------------------------
__global__ __launch_bounds__(256) void k_node(
    const float* __restrict__ x,
    const float* __restrict__ st_b, const float* __restrict__ nt_b,
    float* __restrict__ ws)
{
  __shared__ __align__(16) unsigned char sA[64*512];   // 32 KB
  const int t = threadIdx.x;
  const int c0 = blockIdx.x * 64, g0 = blockIdx.y * 64;

  for (int idx = t; idx < 64*64; idx += 256) {
    int row = idx >> 6, kq = idx & 63;
    float4 v = *(const float4*)(x + (size_t)(g0 + row)*CC + kq*4);
    uint2 p; p.x = pk2(v.x, v.y); p.y = pk2(v.z, v.w);
    *(uint2*)(sA + row*512 + swzc(kq >> 1, row)*16 + (kq & 1)*8) = p;
  }
  __syncthreads();

  const int wid = t >> 6, lane = t & 63, l4 = lane >> 4, l16 = lane & 15;
  const unsigned char* WN = (const unsigned char*)(ws + OFF_WN);

  uint4 af[8];
  {
    int row = wid*16 + l16;
    #pragma unroll
    for (int f = 0; f < 8; ++f)
      af[f] = *(const uint4*)(sA + row*512 + swzc(l4 + 4*f, row)*16);
  }

  const int grow = g0 + wid*16 + l16;      // node row this thread owns
  const int bb = grow >> 9, n0 = grow & 511;

  #pragma unroll
  for (int ct = 0; ct < 4; ++ct) {
    int gcolL = c0 + ct*16 + l16;          // weight-fragment lane col
    f32x4 acc = {0.f, 0.f, 0.f, 0.f};
    #pragma unroll
    for (int f = 0; f < 8; ++f) {
      uint4 wfr = *(const uint4*)(WN + (size_t)gcolL*512 + swzc(l4 + 4*f, gcolL)*16);
      acc = mfma_bf16(wfr, af[f], acc);    // swapped: rows = out cols, cols = nodes
    }
    int gcol0 = c0 + ct*16 + l4*4;         // 4 consecutive out cols this thread holds
    if (gcol0 < 256) {
      f32x4 bz = *(const f32x4*)(st_b + gcol0);
      f32x4 v = acc + bz;
      *(f32x4*)(ws + OFF_SF + (size_t)grow*OO + gcol0) = v;
    } else if (gcol0 < 512) {
      int c = gcol0 - 256;
      f32x4 bz = *(const f32x4*)(nt_b + c);
      #pragma unroll
      for (int r = 0; r < 4; ++r)
        ws[OFF_NBR + ((size_t)bb*256 + c + r)*512 + n0] = acc[r] + bz[r];
    } else if (gcol0 < 576) {
      *(f32x4*)(ws + OFF_AI + (size_t)grow*64 + (gcol0-512)) = acc;
    } else if (gcol0 < 640) {
      *(f32x4*)(ws + OFF_AJ + (size_t)grow*64 + (gcol0-576)) = acc;
    } else {
      *(f32x4*)(ws + OFF_EGX + (size_t)grow*64 + (gcol0-640)) = acc;
    }
  }
}

// ---------------------------------------------------------------------------
// k_edge: fused per-row edge kernel, full-MFMA, SWAPPED operands for L1-L5:
// thread holds 1 j-row x 4 consecutive cols -> ds_write_b64 + cvt_pk stores.
// L7 keeps the original orientation (NBR^T, f32x4 attn reads).
// ---------------------------------------------------------------------------
__global__ __launch_bounds__(512, 2) void k_edge(
    const int*   __restrict__ adj,
    const float* __restrict__ ef_g,
    const unsigned char* __restrict__ wimg,
    const float* __restrict__ em_b1g, const float* __restrict__ em_b2g,
    const float* __restrict__ em_b3g,
    const float* __restrict__ at_b1g, const float* __restrict__ at_b2g,
    const float* __restrict__ at_w3g, const float* __restrict__ at_b3g,
    const float* __restrict__ eg_b1g, const float* __restrict__ eg_b2g,
    float* __restrict__ ws)
{
  __shared__ __align__(16) unsigned char s_act[512*128];   // 64 KB activation bounce
  __shared__ __align__(16) float s_bem1[64], s_bem2[64], s_bem3[32];
  __shared__ __align__(16) float s_t1init[64], s_bat2[32], s_w3[32];
  __shared__ __align__(16) float s_beg1[64], s_beg2[256];
  __shared__ __align__(16) float s_sc[512];
  __shared__ float s_red[8];
  __shared__ float s_msg[8][256];

  const int t = threadIdx.x;
  const int i = blockIdx.x, b = blockIdx.y;
  const int wid = t >> 6, lane = t & 63, l4 = lane >> 4, l16 = lane & 15;
  const int R = wid * 64;

  const unsigned char* Wem1 = wimg;
  const unsigned char* Wem2 = wimg + 8192;
  const unsigned char* Wem3 = wimg + 16384;
  const unsigned char* Wat1 = wimg + 20480;
  const unsigned char* Wat2 = wimg + 28672;
  const unsigned char* Weg1 = wimg + 32768;
  const unsigned char* Weg2 = wimg + 40960;

  if (t < 64) {
    s_bem1[t]   = em_b1g[t];
    s_bem2[t]   = em_b2g[t];
    s_t1init[t] = ws[OFF_AI + (size_t)(b*NN + i)*64 + t] + at_b1g[t];
    s_beg1[t]   = eg_b1g[t];
  } else if (t < 96)  { s_bem3[t-64]  = em_b3g[t-64]; }
  else if (t < 128)   { s_bat2[t-96]  = at_b2g[t-96]; }
  else if (t < 160)   { s_w3[t-128]   = at_w3g[t-128]; }
  if (t < 256) s_beg2[t] = eg_b2g[t];
  const float atb3 = at_b3g[0];

  const float maskf = adj[(size_t)(b*NN + i)*NN + t] > 0 ? 1.f : 0.f;

  // stage ef row (pad 18 -> 32, bf16, swizzled)
  {
    const int j = t;
    const float* efp = ef_g + ((size_t)(b*NN + i)*NN + j) * EE;
    float e[32];
    #pragma unroll
    for (int k = 0; k < 9; ++k) { float2 v2 = *(const float2*)(efp + 2*k); e[2*k] = v2.x; e[2*k+1] = v2.y; }
    #pragma unroll
    for (int k = EE; k < 32; ++k) e[k] = 0.f;
    #pragma unroll
    for (int c = 0; c < 4; ++c) {
      uint4 u = make_uint4(pk2(e[c*8+0],e[c*8+1]), pk2(e[c*8+2],e[c*8+3]),
                           pk2(e[c*8+4],e[c*8+5]), pk2(e[c*8+6],e[c*8+7]));
      *(uint4*)(s_act + j*128 + ((c ^ (j & 7)) << 4)) = u;
    }
  }
  __syncthreads();

  auto loadA = [&](int rb, int f) -> uint4 {      // act fragment (B operand now)
    int rw = rb + l16;
    return *(const uint4*)(s_act + rw*128 + (((l4 + 4*f) ^ (rw & 7)) << 4));
  };
  auto loadB = [&](const unsigned char* w, int ct, int f) -> uint4 {  // weight frag (A operand now)
    int rw = ct*16 + l16;
    return *(const uint4*)(w + rw*128 + (((l4 + 4*f) ^ (rw & 7)) << 4));
  };
  // swapped-C store: thread holds row j = rb+l16, cols ct*16+l4*4 .. +3
  auto storeCT = [&](int rb, int ct, const f32x4& c) {
    int rw = rb + l16;
    int col0 = ct*16 + l4*4;
    uint2 v;
    v.x = cvtpk(fmaxf(c[0], 0.f), fmaxf(c[1], 0.f));
    v.y = cvtpk(fmaxf(c[2], 0.f), fmaxf(c[3], 0.f));
    *(uint2*)(s_act + rw*128 + swzc(col0 >> 3, rw)*16 + (col0 & 7)*2) = v;
  };

  const float* ajR  = ws + OFF_AJ  + (size_t)b*NN*64;     // row-major [row][64]
  const float* egR  = ws + OFF_EGX + (size_t)b*NN*64;     // row-major [row][64]
  const float* nbrT = ws + OFF_NBR + (size_t)b*256*512;   // transposed [col][row]

  uint4 peA[4];

  // ---- L1: ef(K32) -> h1(64) ----
  {
    uint4 W[4];
    #pragma unroll
    for (int ct = 0; ct < 4; ++ct) W[ct] = loadB(Wem1, ct, 0);
    #pragma unroll
    for (int st = 0; st < 4; ++st) {
      int rb = R + st*16;
      uint4 a = loadA(rb, 0);
      #pragma unroll
      for (int ct = 0; ct < 4; ++ct) {
        f32x4 c = *(const f32x4*)&s_bem1[ct*16 + l4*4];
        c = mfma_bf16(W[ct], a, c);
        storeCT(rb, ct, c);
      }
    }
  }
  // ---- L2: h1(K64) -> h2(64) ----
  {
    uint4 W[4][2];
    #pragma unroll
    for (int ct = 0; ct < 4; ++ct) { W[ct][0] = loadB(Wem2, ct, 0); W[ct][1] = loadB(Wem2, ct, 1); }
    #pragma unroll
    for (int st = 0; st < 4; ++st) {
      int rb = R + st*16;
      uint4 a0 = loadA(rb, 0), a1 = loadA(rb, 1);
      #pragma unroll
      for (int ct = 0; ct < 4; ++ct) {
        f32x4 c = *(const f32x4*)&s_bem2[ct*16 + l4*4];
        c = mfma_bf16(W[ct][0], a0, c);
        c = mfma_bf16(W[ct][1], a1, c);
        storeCT(rb, ct, c);
      }
    }
  }
  // ---- L3: h2(K64) -> pe(32); keep pe act-frags in registers ----
  {
    uint4 W[2][2];
    #pragma unroll
    for (int ct = 0; ct < 2; ++ct) { W[ct][0] = loadB(Wem3, ct, 0); W[ct][1] = loadB(Wem3, ct, 1); }
    #pragma unroll
    for (int st = 0; st < 4; ++st) {
      int rb = R + st*16;
      uint4 a0 = loadA(rb, 0), a1 = loadA(rb, 1);
      #pragma unroll
      for (int ct = 0; ct < 2; ++ct) {
        f32x4 c = *(const f32x4*)&s_bem3[ct*16 + l4*4];
        c = mfma_bf16(W[ct][0], a0, c);
        c = mfma_bf16(W[ct][1], a1, c);
        storeCT(rb, ct, c);
      }
      peA[st] = loadA(rb, 0);
    }
  }
  // ---- L4a: t1 = relu(a_i + a_j + b1 + pe @ at_w1e) ----
  {
    uint4 W[4];
    #pragma unroll
    for (int ct = 0; ct < 4; ++ct) W[ct] = loadB(Wat1, ct, 0);
    #pragma unroll
    for (int st = 0; st < 4; ++st) {
      int rb = R + st*16;
      int j = rb + l16;
      #pragma unroll
      for (int ct = 0; ct < 4; ++ct) {
        int col0 = ct*16 + l4*4;
        f32x4 ti = *(const f32x4*)&s_t1init[col0];
        f32x4 av = *(const f32x4*)(ajR + (size_t)j*64 + col0);
        f32x4 c = ti + av;
        c = mfma_bf16(W[ct], peA[st], c);
        storeCT(rb, ct, c);
      }
    }
  }
  // ---- L5: t2 = relu(t1 @ at_w2 + b2); score = t2 . w3 + b3 ----
  {
    uint4 W[2][2];
    #pragma unroll
    for (int ct = 0; ct < 2; ++ct) { W[ct][0] = loadB(Wat2, ct, 0); W[ct][1] = loadB(Wat2, ct, 1); }
    #pragma unroll
    for (int st = 0; st < 4; ++st) {
      int rb = R + st*16;
      uint4 a0 = loadA(rb, 0), a1 = loadA(rb, 1);
      f32x4 c0 = *(const f32x4*)&s_bat2[l4*4];
      f32x4 c1 = *(const f32x4*)&s_bat2[16 + l4*4];
      c0 = mfma_bf16(W[0][0], a0, c0); c0 = mfma_bf16(W[0][1], a1, c0);
      c1 = mfma_bf16(W[1][0], a0, c1); c1 = mfma_bf16(W[1][1], a1, c1);
      float val = 0.f;
      #pragma unroll
      for (int r = 0; r < 4; ++r) {
        val += fmaxf(c0[r], 0.f)*s_w3[l4*4 + r];
        val += fmaxf(c1[r], 0.f)*s_w3[16 + l4*4 + r];
      }
      val += __shfl_xor(val, 16);
      val += __shfl_xor(val, 32);
      if (l4 == 0) s_sc[rb + l16] = val + atb3;
    }
  }
  // ---- L4b: g1 = relu(eg_x_j + eg_b1 + pe @ eg_w1e) -> s_act ----
  {
    uint4 W[4];
    #pragma unroll
    for (int ct = 0; ct < 4; ++ct) W[ct] = loadB(Weg1, ct, 0);
    #pragma unroll
    for (int st = 0; st < 4; ++st) {
      int rb = R + st*16;
      int j = rb + l16;
      #pragma unroll
      for (int ct = 0; ct < 4; ++ct) {
        int col0 = ct*16 + l4*4;
        f32x4 bg = *(const f32x4*)&s_beg1[col0];
        f32x4 ev = *(const f32x4*)(egR + (size_t)j*64 + col0);
        f32x4 c = bg + ev;
        c = mfma_bf16(W[ct], peA[st], c);
        storeCT(rb, ct, c);
      }
    }
  }
  __syncthreads();

  // ---------------- masked softmax over j ----------------
  {
    float v  = maskf > 0.f ? s_sc[t] : -1e9f;
    float m = v;
    #pragma unroll
    for (int d = 1; d < 64; d <<= 1) m = fmaxf(m, __shfl_xor(m, d));
    if (lane == 0) s_red[wid] = m;
    __syncthreads();
    float mx = s_red[0];
    #pragma unroll
    for (int w = 1; w < 8; ++w) mx = fmaxf(mx, s_red[w]);
    float p = maskf > 0.f ? __expf(v - mx) : 0.f;
    float sm = p;
    #pragma unroll
    for (int d = 1; d < 64; d <<= 1) sm += __shfl_xor(sm, d);
    __syncthreads();
    if (lane == 0) s_red[wid] = sm;
    __syncthreads();
    float den = 0.f;
    #pragma unroll
    for (int w = 0; w < 8; ++w) den += s_red[w];
    float inv = den > 0.f ? 1.f/den : 0.f;
    s_sc[t] = p * inv;
  }
  __syncthreads();

  // ---- L7 (original orientation): z = g1 @ eg_w2 + b2; msg += sig(z)*attn*nbr ----
  {
    uint4 gA[4][2];
    #pragma unroll
    for (int st = 0; st < 4; ++st) { gA[st][0] = loadA(R + st*16, 0); gA[st][1] = loadA(R + st*16, 1); }

    for (int ct = 0; ct < 16; ++ct) {
      uint4 B0 = loadB(Weg2, ct, 0), B1 = loadB(Weg2, ct, 1);
      int col = ct*16 + l16;
      float bz = s_beg2[col];
      const float* nbrc = nbrT + (size_t)col*512 + R + l4*4;
      float msgp = 0.f;
      #pragma unroll
      for (int st = 0; st < 4; ++st) {
        f32x4 nv = *(const f32x4*)(nbrc + st*16);
        f32x4 at = *(const f32x4*)(&s_sc[R + st*16 + l4*4]);
        f32x4 c = {bz, bz, bz, bz};
        c = mfma_bf16(gA[st][0], B0, c);
        c = mfma_bf16(gA[st][1], B1, c);
        #pragma unroll
        for (int r = 0; r < 4; ++r) {
          float g = __builtin_amdgcn_rcpf(1.f + __expf(-c[r]));
          msgp += g * at[r] * nv[r];
        }
      }
      msgp += __shfl_xor(msgp, 16);
      msgp += __shfl_xor(msgp, 32);
      if (lane < 16) s_msg[wid][ct*16 + lane] = msgp;
    }
  }
  __syncthreads();
  if (t < 256) {
    float s = 0.f;
    #pragma unroll
    for (int w = 0; w < 8; ++w) s += s_msg[w][t];
    ws[OFF_MSG + (size_t)(b*NN + i)*OO + t] = s;
  }
}

// ---------------------------------------------------------------------------
// k_out (MFMA): unchanged.
// ---------------------------------------------------------------------------
__global__ __launch_bounds__(256) void k_out(
    const float* __restrict__ cb_b1, const float* __restrict__ cb_b2,
    const float* __restrict__ ws, float* __restrict__ out)
{
  __shared__ __align__(16) unsigned char sA[16*1024];
  __shared__ __align__(16) unsigned char sT[16*512];
  const int t = threadIdx.x;
  const int g0 = blockIdx.x * 16;

  for (int idx = t; idx < 16*128; idx += 256) {
    int row = idx >> 7, kq = idx & 127;
    const float* src = (kq < 64)
        ? ws + OFF_SF  + (size_t)(g0 + row)*OO + kq*4
        : ws + OFF_MSG + (size_t)(g0 + row)*OO + (kq - 64)*4;
    float4 v = *(const float4*)src;
    uint2 p; p.x = pk2(v.x, v.y); p.y = pk2(v.z, v.w);
    *(uint2*)(sA + row*1024 + swzc(kq >> 1, row)*16 + (kq & 1)*8) = p;
  }
  __syncthreads();

  const int wid = t >> 6, lane = t & 63, l4 = lane >> 4, l16 = lane & 15;
  const unsigned char* W1 = (const unsigned char*)(ws + OFF_W1);
  const unsigned char* W2 = (const unsigned char*)(ws + OFF_W2);

  {
    uint4 af[16];
    #pragma unroll
    for (int f = 0; f < 16; ++f)
      af[f] = *(const uint4*)(sA + l16*1024 + swzc(l4 + 4*f, l16)*16);
    #pragma unroll
    for (int c = 0; c < 4; ++c) {
      int col = wid*64 + c*16 + l16;
      float bz = cb_b1[col];
      f32x4 acc = {bz, bz, bz, bz};
      #pragma unroll
      for (int f = 0; f < 16; ++f) {
        uint4 bfr = *(const uint4*)(W1 + (size_t)col*1024 + swzc(l4 + 4*f, col)*16);
        acc = mfma_bf16(af[f], bfr, acc);
      }
      #pragma unroll
      for (int r = 0; r < 4; ++r) {
        int row = l4*4 + r;
        *(unsigned short*)(sT + row*512 + swzc(col >> 3, row)*16 + (col & 7)*2)
            = f2bf(fmaxf(acc[r], 0.f));
      }
    }
  }
  __syncthreads();

  {
    uint4 tf[8];
    #pragma unroll
    for (int f = 0; f < 8; ++f)
      tf[f] = *(const uint4*)(sT + l16*512 + swzc(l4 + 4*f, l16)*16);
    #pragma unroll
    for (int c = 0; c < 4; ++c) {
      int col = wid*64 + c*16 + l16;
      float bz = cb_b2[col];
      f32x4 acc = {bz, bz, bz, bz};
      #pragma unroll
      for (int f = 0; f < 8; ++f) {
        uint4 bfr = *(const uint4*)(W2 + (size_t)col*512 + swzc(l4 + 4*f, col)*16);
        acc = mfma_bf16(tf[f], bfr, acc);
      }
      #pragma unroll
      for (int r = 0; r < 4; ++r)
        out[(size_t)(g0 + l4*4 + r)*OO + col] = acc[r];
    }
  }
}

extern "C" void kernel_launch(void* const* d_in, const int* in_sizes, int n_in,
                              void* d_out, int out_size, void* d_ws, size_t ws_size,
                              hipStream_t stream) {
  const float* x     = (const float*)d_in[0];
  const int*   adj   = (const int*)  d_in[1];
  const float* ef    = (const float*)d_in[2];
  const float* st_w  = (const float*)d_in[3];
  const float* st_b  = (const float*)d_in[4];
  const float* nt_w  = (const float*)d_in[5];
  const float* nt_b  = (const float*)d_in[6];
  const float* em_w1 = (const float*)d_in[7];
  const float* em_b1 = (const float*)d_in[8];
  const float* em_w2 = (const float*)d_in[9];
  const float* em_b2 = (const float*)d_in[10];
  const float* em_w3 = (const float*)d_in[11];
  const float* em_b3 = (const float*)d_in[12];
  const float* at_w1 = (const float*)d_in[13];
  const float* at_b1 = (const float*)d_in[14];
  const float* at_w2 = (const float*)d_in[15];
  const float* at_b2 = (const float*)d_in[16];
  const float* at_w3 = (const float*)d_in[17];
  const float* at_b3 = (const float*)d_in[18];
  const float* eg_w1 = (const float*)d_in[19];
  const float* eg_b1 = (const float*)d_in[20];
  const float* eg_w2 = (const float*)d_in[21];
  const float* eg_b2 = (const float*)d_in[22];
  const float* cb_w1 = (const float*)d_in[23];
  const float* cb_b1 = (const float*)d_in[24];
  const float* cb_w2 = (const float*)d_in[25];
  const float* cb_b2 = (const float*)d_in[26];
  float* ws  = (float*)d_ws;
  float* out = (float*)d_out;
  unsigned char* wimg = (unsigned char*)d_out;   // dead until k_out overwrites

  k_prep_w<<<dim3(208), dim3(256), 0, stream>>>(em_w1, em_w2, em_w3, at_w1, at_w2,
      eg_w1, eg_w2, st_w, nt_w, wimg, ws);
  k_node<<<dim3(11, 16), dim3(256), 0, stream>>>(x, st_b, nt_b, ws);
  k_edge<<<dim3(NN, BB), dim3(512), 0, stream>>>(adj, ef, wimg,
      em_b1, em_b2, em_b3, at_b1, at_b2, at_w3, at_b3, eg_b1, eg_b2, ws);
  k_prep_out<<<dim3(96), dim3(256), 0, stream>>>(cb_w1, cb_w2, ws);
  k_out<<<dim3(64), dim3(256), 0, stream>>>(cb_b1, cb_b2, ws, out);
}